// Round 9
// baseline (247.422 us; speedup 1.0000x reference)
//
#include <hip/hip_runtime.h>
#include <hip/hip_bf16.h>

// ---------------------------------------------------------------------------
// Recommender pipeline.
//  K0 detect : bf16-vs-f32 flag in ws[0]
//  K1 prep   : weights -> ws; K-PACKED f32 for news/mlp GEMMs; Wanc/Waw1
//              SPLIT-BF16 frag-packed [kt][n][16] hi/lo for MFMA.
//  K2 news   : news_e = tanh(elu(title@W1^T+b)@W2^T+b)        [3520,128]
//  K3 gather : X[n] = [ent[node], sum_k(ent[adj]+rel[radj])]  [70400,256]
//              split-bf16, MFMA A-frag order. R8 post-mortem: k_gather is
//              the #1 kernel (95us): 198MB FETCH (= 774k x 256B random
//              entity-row gathers, zero L2 reuse) at only 2.1 TB/s with
//              occ 37.5%, VALU 13% -> request-concurrency bound. R9: max
//              TLP -- 8 rows/block (1 row/32-lane group, NO outer loop),
//              LDS 8.4KB, VGPR<=64 -> up to 32 waves/CU, 2.7x the gathers
//              in flight.
//  K4 anchor : MFMA (v_mfma_f32_32x32x16_bf16) 3-term split-bf16,
//              frag-ordered coalesced A, LDS exactly 80KB -> 2 blocks/CU.
//  K5 mlp    : elu(elu([news_e,AE]@Wm1^T+b)@Wm2^T+b)          [3520,128]
//  K6 score  : user mean + dot                                 [64,5]
// ---------------------------------------------------------------------------

#define B_ 64
#define S_ 5
#define UC_ 50
#define A_ 20
#define NCAND 320
#define NCLK 3200
#define NNEWS 3520
#define NANCH 70400

// ws layout (float indices)
static constexpr long OFF_WNC1P = 64;        // [192][128][4] f32
static constexpr long OFF_BNC1  = 98368;
static constexpr long OFF_WNC2P = 98496;     // [32][128][4] f32
static constexpr long OFF_BNC2  = 114880;
static constexpr long OFF_WANCP = 115008;    // [16kt][128n][16k] bf16 hi + lo (65536 ushort)
static constexpr long OFF_BANC  = 147776;
static constexpr long OFF_WAW1P = 147904;    // [8kt][128n][16k] bf16 hi + lo (32768 ushort)
static constexpr long OFF_BAW1  = 164288;
static constexpr long OFF_WAW2  = 164416;    // [128]
static constexpr long OFF_BAW2  = 164544;    // [1]
static constexpr long OFF_WM1P  = 164548;    // [64][128][4] f32
static constexpr long OFF_BM1   = 197316;
static constexpr long OFF_WM2P  = 197444;    // [32][128][4] f32
static constexpr long OFF_BM2   = 213828;
static constexpr long OFF_REL   = 213956;    // [100][128] f32
static constexpr long OFF_AE    = 226756;    // [3520][128] f32
static constexpr long OFF_NE    = 677316;    // [3520][128] f32
static constexpr long OFF_MO    = 1127876;   // [3520][128] f32 (k_anchor LG scratch, then k_mlp out)
static constexpr long OFF_X     = 1578436;   // XH[2200][8192] + XL[2200][8192] ushort frag-order
// total ~19.6M floats = 78.4 MB

typedef __attribute__((ext_vector_type(8))) short short8v;   // 8 bf16 = 4 VGPR
typedef __attribute__((ext_vector_type(16))) float f32x16;   // MFMA 32x32 acc

__device__ __forceinline__ float ldf(const void* p, long i, int bf) {
  if (bf) {
    unsigned int u = (unsigned int)((const unsigned short*)p)[i];
    u <<= 16;
    return __uint_as_float(u);
  }
  return ((const float*)p)[i];
}

// 4 consecutive elems starting at i (i % 4 == 0)
__device__ __forceinline__ float4 ldf4(const void* p, long i, int bf) {
  float4 f;
  if (bf) {
    const unsigned short* q = (const unsigned short*)p + i;
    uint2 u = *(const uint2*)q;
    f.x = __uint_as_float(u.x << 16);
    f.y = __uint_as_float(u.x & 0xffff0000u);
    f.z = __uint_as_float(u.y << 16);
    f.w = __uint_as_float(u.y & 0xffff0000u);
  } else {
    f = *(const float4*)((const float*)p + i);
  }
  return f;
}

__device__ __forceinline__ float eluf(float v) { return v > 0.f ? v : expm1f(v); }

// split f32 v into hi (truncated bf16 bits) + lo (RNE bf16 of remainder)
__device__ __forceinline__ void splitbf(float v, unsigned short& hi, unsigned short& lo) {
  unsigned int b = __float_as_uint(v);
  hi = (unsigned short)(b >> 16);
  float rm = v - __uint_as_float(b & 0xffff0000u);
  unsigned int rb = __float_as_uint(rm);
  lo = (unsigned short)((rb + 0x7fffu + ((rb >> 16) & 1u)) >> 16);
}

__device__ __forceinline__ float bfh(unsigned short u) {
  return __uint_as_float((unsigned int)u << 16);
}

// ---- K0: dtype detect -----------------------------------------------------
__global__ void k_detect(const void* ent, int* flag) {
  __shared__ int cnt;
  if (threadIdx.x == 0) cnt = 0;
  __syncthreads();
  unsigned short u = ((const unsigned short*)ent)[threadIdx.x];
  int e = (u >> 7) & 0xFF;
  int ok = (e >= 107 && e <= 146) ? 1 : 0;
  atomicAdd(&cnt, ok);
  __syncthreads();
  if (threadIdx.x == 0) *flag = (cnt >= 200) ? 1 : 0;
}

// ---- K1: convert weights --------------------------------------------------
// MD 0: plain f32. MD 2: f32 K-packed [k/4][128][4]. MD 3: split-bf16 MFMA
// B-frag pack [kt][n][16k] hi then lo.
__global__ __launch_bounds__(256) void k_prep(
    const void* s0, const void* s1, const void* s2, const void* s3,
    const void* s4, const void* s5, const void* s6, const void* s7,
    const void* s8, const void* s9, const void* s10, const void* s11,
    const void* s12, const void* s13, const void* s14, float* ws) {
  const int bf = ((const int*)ws)[0];
  const void* srcs[15] = {s0,s1,s2,s3,s4,s5,s6,s7,s8,s9,s10,s11,s12,s13,s14};
  const int R[15] = {128,128,128,128,128,128,128,128,1,  1,  128,128,128,128,100};
  const int C[15] = {768,1,  128,1,  256,1,  128,1,  128,1,  256,1,  128,1,  128};
  const int MD[15]= {2,  0,  2,  0,  3,  0,  3,  0,  0,  0,  2,  0,  2,  0,  0};
  const long OFF[15] = {OFF_WNC1P,OFF_BNC1,OFF_WNC2P,OFF_BNC2,OFF_WANCP,OFF_BANC,
                        OFF_WAW1P,OFF_BAW1,OFF_WAW2,OFF_BAW2,OFF_WM1P,OFF_BM1,
                        OFF_WM2P,OFF_BM2,OFF_REL};
  const long total = 226689;
  for (long idx = (long)blockIdx.x * blockDim.x + threadIdx.x; idx < total;
       idx += (long)gridDim.x * blockDim.x) {
    long rem = idx;
    int s = 0;
    while (rem >= (long)R[s] * C[s]) { rem -= (long)R[s] * C[s]; s++; }
    float v = ldf(srcs[s], rem, bf);
    if (MD[s] == 2) {
      long r = rem / C[s], c = rem - r * C[s];
      ws[OFF[s] + (c >> 2) * 512 + r * 4 + (c & 3)] = v;
    } else if (MD[s] == 3) {
      long r = rem / C[s], c = rem - r * C[s];   // r = out n, c = k
      unsigned short hi, lo;
      splitbf(v, hi, lo);
      unsigned short* H = (unsigned short*)(ws + OFF[s]);
      unsigned short* L = H + (s == 4 ? 32768 : 16384);
      long id2 = ((c >> 4) * 128 + r) * 16 + (c & 15);
      H[id2] = hi;
      L[id2] = lo;
    } else {
      ws[OFF[s] + rem] = v;
    }
  }
}

// ---- K2: news title MLP (128 thr, 8 rows, acc[8]) ------------------------
__global__ __launch_bounds__(128) void k_news(const void* titles, const int* cand,
                                              const int* clk, float* ws) {
  const int bf = ((const int*)ws)[0];
  __shared__ __align__(16) float t[8][768];
  __shared__ __align__(16) float h1[8][128];
  int tid = threadIdx.x;
  long r0 = (long)blockIdx.x * 8;
  for (int x = tid * 4; x < 8 * 768; x += 128 * 4) {
    int c = x / 768, k = x - c * 768;
    long i = r0 + c;
    int id = (i < NCAND) ? cand[i] : clk[i - NCAND];
    *(float4*)&t[c][k] = ldf4(titles, (long)id * 768 + k, bf);
  }
  __syncthreads();
  int j = tid;
  const float4* W1 = (const float4*)(ws + OFF_WNC1P);
  float acc[8];
#pragma unroll
  for (int c = 0; c < 8; c++) acc[c] = 0.f;
  for (int k4 = 0; k4 < 192; k4++) {
    float4 w = W1[k4 * 128 + j];
#pragma unroll
    for (int c = 0; c < 8; c++) {
      const float4 xv = *(const float4*)&t[c][k4 * 4];
      acc[c] += w.x * xv.x + w.y * xv.y + w.z * xv.z + w.w * xv.w;
    }
  }
  float b1 = ws[OFF_BNC1 + j];
#pragma unroll
  for (int c = 0; c < 8; c++) h1[c][j] = eluf(acc[c] + b1);
  __syncthreads();
  const float4* W2 = (const float4*)(ws + OFF_WNC2P);
  float a2[8];
#pragma unroll
  for (int c = 0; c < 8; c++) a2[c] = 0.f;
  for (int k4 = 0; k4 < 32; k4++) {
    float4 w = W2[k4 * 128 + j];
#pragma unroll
    for (int c = 0; c < 8; c++) {
      const float4 xv = *(const float4*)&h1[c][k4 * 4];
      a2[c] += w.x * xv.x + w.y * xv.y + w.z * xv.z + w.w * xv.w;
    }
  }
  float b2 = ws[OFF_BNC2 + j];
  float* NE = ws + OFF_NE;
#pragma unroll
  for (int c = 0; c < 8; c++) NE[(r0 + c) * 128 + j] = tanhf(a2[c] + b2);
}

// ---- K3: gather -> split-bf16 X in MFMA A-frag order ----------------------
// MAX-TLP: 8 rows/block (grid 8800), one row per 32-lane group, no outer
// loop -> every wave has ~11 independent gathers in flight; LDS 8.4KB and
// VGPR<=64 allow up to 32 waves/CU. Frag order: XH[rt*8192 + kt2h*256 +
// ln*8 + e], rt = b>>2, ln = (b&3)*8 + row.
__global__ __launch_bounds__(256) void k_gather(const void* ent, const int* canda,
                                                const int* clka, const int* eadj,
                                                const int* radj, float* ws) {
  const int bf = ((const int*)ws)[0];
  __shared__ __align__(16) unsigned short XbH[8][264];
  __shared__ __align__(16) unsigned short XbL[8][264];
  int tid = threadIdx.x;
  int lane = tid & 31;
  int row = tid >> 5;                 // 8 groups, one row each
  const float* relf = ws + OFF_REL;

  long n = (long)blockIdx.x * 8 + row;
  int node = (n < (long)NCAND * A_) ? canda[n] : clka[n - (long)NCAND * A_];
  int idx = 0;
  if (lane < 10) idx = eadj[(long)node * 10 + lane];
  else if (lane < 20) idx = radj[(long)node * 10 + (lane - 10)];
  int an[10], rn[10];
#pragma unroll
  for (int k = 0; k < 10; k++) {
    an[k] = __shfl(idx, k, 32);
    rn[k] = __shfl(idx, k + 10, 32);
  }
  float4 x1 = ldf4(ent, (long)node * 128 + lane * 4, bf);
  float4 acc = {0.f, 0.f, 0.f, 0.f};
#pragma unroll
  for (int k = 0; k < 10; k++) {
    float4 e = ldf4(ent, (long)an[k] * 128 + lane * 4, bf);
    const float4 r = *(const float4*)&relf[(long)rn[k] * 128 + lane * 4];
    acc.x += e.x + r.x;
    acc.y += e.y + r.y;
    acc.z += e.z + r.z;
    acc.w += e.w + r.w;
  }
  ushort4 h4, l4;
  splitbf(x1.x, h4.x, l4.x); splitbf(x1.y, h4.y, l4.y);
  splitbf(x1.z, h4.z, l4.z); splitbf(x1.w, h4.w, l4.w);
  *(ushort4*)&XbH[row][lane * 4] = h4;
  *(ushort4*)&XbL[row][lane * 4] = l4;
  splitbf(acc.x, h4.x, l4.x); splitbf(acc.y, h4.y, l4.y);
  splitbf(acc.z, h4.z, l4.z); splitbf(acc.w, h4.w, l4.w);
  *(ushort4*)&XbH[row][128 + lane * 4] = h4;
  *(ushort4*)&XbL[row][128 + lane * 4] = l4;
  __syncthreads();

  unsigned short* XH = (unsigned short*)(ws + OFF_X);
  unsigned short* XL = XH + (size_t)NANCH * 256;
  int b = blockIdx.x;
  long base = (long)(b >> 2) * 8192 + (long)(b & 3) * 64;  // ln0*8 = (b&3)*8*8
  {
    int lr = tid & 7, kt2h = tid >> 3;   // 256 chunks exactly
    long addr = base + (long)kt2h * 256 + (long)lr * 8;
    *(uint4*)&XH[addr] = *(const uint4*)&XbH[lr][kt2h * 8];
    *(uint4*)&XL[addr] = *(const uint4*)&XbL[lr][kt2h * 8];
  }
}

// ---- K4: MFMA anchor GEMMs + softmax -------------------------------------
// block = 8 news = 160 rows (5 M-tiles), 256 thr = 4 waves; wave w = N-tile
// w (cols w*32..+31). A-frag loads fully coalesced via K3's frag order.
// LDS = Hhi+Hlo = exactly 80KB -> 2 blocks/CU. Logit partials go to global
// scratch (MO region, dead until k_mlp). C/D map (m74/m101): col = l&31,
// row = (reg&3) + 8*(reg>>2) + 4*(l>>5).
__global__ __launch_bounds__(256, 2) void k_anchor(float* ws) {
  __shared__ __align__(16) unsigned short Hhi[160][128];  // 40 KB
  __shared__ __align__(16) unsigned short Hlo[160][128];  // 40 KB
  int tid = threadIdx.x;
  int lane = tid & 63, wv = tid >> 6;
  int ln = lane & 31, kh = lane >> 5;
  int col = (wv << 5) + ln;

  const unsigned short* XH = (const unsigned short*)(ws + OFF_X);
  const unsigned short* XL = XH + (size_t)NANCH * 256;
  const unsigned short* WAH = (const unsigned short*)(ws + OFF_WANCP);
  const unsigned short* WAL = WAH + 32768;
  const unsigned short* W1H = (const unsigned short*)(ws + OFF_WAW1P);
  const unsigned short* W1L = W1H + 16384;
  float* LGs = ws + OFF_MO + (long)blockIdx.x * 640;  // [4][160] per-wave partials

  // --- Stage B: H = tanh(X @ Wanc^T + b), [160,256]@[256->128] ---
  {
    f32x16 acc[5] = {};
    for (int kt = 0; kt < 16; ++kt) {
      long wi = ((long)(kt * 128 + col) << 4) + (kh << 3);
      short8v bhi = *(const short8v*)(WAH + wi);
      short8v blo = *(const short8v*)(WAL + wi);
#pragma unroll
      for (int mt = 0; mt < 5; ++mt) {
        long ai = ((long)(blockIdx.x * 5 + mt) << 13) + ((kt * 2 + kh) << 8) + (ln << 3);
        short8v ahi = *(const short8v*)(XH + ai);
        short8v alo = *(const short8v*)(XL + ai);
        acc[mt] = __builtin_amdgcn_mfma_f32_32x32x16_bf16(ahi, bhi, acc[mt], 0, 0, 0);
        acc[mt] = __builtin_amdgcn_mfma_f32_32x32x16_bf16(ahi, blo, acc[mt], 0, 0, 0);
        acc[mt] = __builtin_amdgcn_mfma_f32_32x32x16_bf16(alo, bhi, acc[mt], 0, 0, 0);
      }
    }
    float bc = ws[OFF_BANC + col];
#pragma unroll
    for (int mt = 0; mt < 5; ++mt)
#pragma unroll
      for (int j = 0; j < 16; ++j) {
        int r = mt * 32 + (j & 3) + ((j >> 2) << 3) + (kh << 2);
        float h = tanhf(acc[mt][j] + bc);
        unsigned short hi, lo;
        splitbf(h, hi, lo);
        int sc = col ^ ((r & 7) << 3);   // T2 XOR swizzle (16B granules)
        Hhi[r][sc] = hi;
        Hlo[r][sc] = lo;
      }
  }
  __syncthreads();

  // --- Stage C: logits = elu(H@Waw1^T+b1)@w2 + b2, [160,128]@[128->128] ---
  {
    f32x16 ac[5] = {};
    for (int kt = 0; kt < 8; ++kt) {
      long wi = ((long)(kt * 128 + col) << 4) + (kh << 3);
      short8v bhi = *(const short8v*)(W1H + wi);
      short8v blo = *(const short8v*)(W1L + wi);
#pragma unroll
      for (int mt = 0; mt < 5; ++mt) {
        int rr = mt * 32 + ln;
        int kb = (kt * 16 + (kh << 3)) ^ ((rr & 7) << 3);
        short8v ahi = *(const short8v*)&Hhi[rr][kb];
        short8v alo = *(const short8v*)&Hlo[rr][kb];
        ac[mt] = __builtin_amdgcn_mfma_f32_32x32x16_bf16(ahi, bhi, ac[mt], 0, 0, 0);
        ac[mt] = __builtin_amdgcn_mfma_f32_32x32x16_bf16(ahi, blo, ac[mt], 0, 0, 0);
        ac[mt] = __builtin_amdgcn_mfma_f32_32x32x16_bf16(alo, bhi, ac[mt], 0, 0, 0);
      }
    }
    float b1c = ws[OFF_BAW1 + col];
    float w2c = ws[OFF_WAW2 + col];
#pragma unroll
    for (int mt = 0; mt < 5; ++mt)
#pragma unroll
      for (int j = 0; j < 16; ++j) {
        int r = mt * 32 + (j & 3) + ((j >> 2) << 3) + (kh << 2);
        float v = eluf(ac[mt][j] + b1c) * w2c;
        v += __shfl_xor(v, 16);
        v += __shfl_xor(v, 8);
        v += __shfl_xor(v, 4);
        v += __shfl_xor(v, 2);
        v += __shfl_xor(v, 1);
        if (ln == 0) LGs[wv * 160 + r] = v;   // lanes 0 and 32 (different r)
      }
  }
  __threadfence_block();
  __syncthreads();

  // --- Stage D: per-news softmax over 20 anchors + weighted sum ---
  {
    int g = tid >> 5, l32 = tid & 31, ar = g * 20;
    float bw2 = ws[OFF_BAW2];
    float e[20], mx = -1e30f;
#pragma unroll
    for (int a = 0; a < 20; ++a) {
      int rr = ar + a;
      e[a] = LGs[rr] + LGs[160 + rr] + LGs[320 + rr] + LGs[480 + rr] + bw2;
      mx = fmaxf(mx, e[a]);
    }
    float s = 0.f;
#pragma unroll
    for (int a = 0; a < 20; ++a) { e[a] = expf(e[a] - mx); s += e[a]; }
    float inv = 1.0f / s;
    float o0 = 0.f, o1 = 0.f, o2 = 0.f, o3 = 0.f;
#pragma unroll
    for (int a = 0; a < 20; ++a) {
      int rr = ar + a, sw = (rr & 7) << 3;
      float w = e[a];
      int d0 = l32 ^ sw, d1 = (l32 + 32) ^ sw, d2 = (l32 + 64) ^ sw, d3 = (l32 + 96) ^ sw;
      o0 += w * (bfh(Hhi[rr][d0]) + bfh(Hlo[rr][d0]));
      o1 += w * (bfh(Hhi[rr][d1]) + bfh(Hlo[rr][d1]));
      o2 += w * (bfh(Hhi[rr][d2]) + bfh(Hlo[rr][d2]));
      o3 += w * (bfh(Hhi[rr][d3]) + bfh(Hlo[rr][d3]));
    }
    float* AE = ws + OFF_AE;
    long ro = ((long)blockIdx.x * 8 + g) * 128;
    AE[ro + l32]      = o0 * inv;
    AE[ro + l32 + 32] = o1 * inv;
    AE[ro + l32 + 64] = o2 * inv;
    AE[ro + l32 + 96] = o3 * inv;
  }
}

// ---- K5: final MLP --------------------------------------------------------
__global__ __launch_bounds__(256) void k_mlp(float* ws) {
  __shared__ __align__(16) float xt[16][256];
  __shared__ __align__(16) float h1[16][128];
  int tid = threadIdx.x;
  long r0 = (long)blockIdx.x * 16;
  const float* NE = ws + OFF_NE;
  const float* AE = ws + OFF_AE;
  for (int x = tid; x < 16 * 256; x += 256) {
    int c = x >> 8, k = x & 255;
    xt[c][k] = (k < 128) ? NE[(r0 + c) * 128 + k] : AE[(r0 + c) * 128 + (k - 128)];
  }
  __syncthreads();
  int j = tid & 127, half = tid >> 7;
  const float4* W1 = (const float4*)(ws + OFF_WM1P);
  float acc[8];
#pragma unroll
  for (int c = 0; c < 8; c++) acc[c] = 0.f;
  for (int k4 = 0; k4 < 64; k4++) {
    float4 w = W1[k4 * 128 + j];
#pragma unroll
    for (int c = 0; c < 8; c++) {
      const float4 xv = *(const float4*)&xt[half * 8 + c][k4 * 4];
      acc[c] += w.x * xv.x + w.y * xv.y + w.z * xv.z + w.w * xv.w;
    }
  }
  float b1 = ws[OFF_BM1 + j];
#pragma unroll
  for (int c = 0; c < 8; c++) h1[half * 8 + c][j] = eluf(acc[c] + b1);
  __syncthreads();
  const float4* W2 = (const float4*)(ws + OFF_WM2P);
  float a2[8];
#pragma unroll
  for (int c = 0; c < 8; c++) a2[c] = 0.f;
  for (int k4 = 0; k4 < 32; k4++) {
    float4 w = W2[k4 * 128 + j];
#pragma unroll
    for (int c = 0; c < 8; c++) {
      const float4 xv = *(const float4*)&h1[half * 8 + c][k4 * 4];
      a2[c] += w.x * xv.x + w.y * xv.y + w.z * xv.z + w.w * xv.w;
    }
  }
  float b2 = ws[OFF_BM2 + j];
  float* MO = ws + OFF_MO;
#pragma unroll
  for (int c = 0; c < 8; c++) MO[(r0 + half * 8 + c) * 128 + j] = eluf(a2[c] + b2);
}

// ---- K6: user mean + scores ----------------------------------------------
__global__ __launch_bounds__(128) void k_score(const float* ws, void* out) {
  const int bf = ((const int*)ws)[0];
  int b = blockIdx.x;
  int d = threadIdx.x;
  const float* MO = ws + OFF_MO;
  float u = 0.f;
  for (int t = 0; t < UC_; t++) u += MO[(long)(NCAND + b * UC_ + t) * 128 + d];
  u *= (1.0f / UC_);
  __shared__ float red[2];
  for (int s = 0; s < S_; s++) {
    float p = MO[(long)(b * S_ + s) * 128 + d] * u;
#pragma unroll
    for (int o = 32; o > 0; o >>= 1) p += __shfl_down(p, o, 64);
    if ((d & 63) == 0) red[d >> 6] = p;
    __syncthreads();
    if (d == 0) {
      float v = red[0] + red[1];
      if (bf)
        ((__hip_bfloat16*)out)[b * S_ + s] = __float2bfloat16(v);
      else
        ((float*)out)[b * S_ + s] = v;
    }
    __syncthreads();
  }
}

extern "C" void kernel_launch(void* const* d_in, const int* in_sizes, int n_in,
                              void* d_out, int out_size, void* d_ws, size_t ws_size,
                              hipStream_t stream) {
  (void)in_sizes; (void)n_in; (void)out_size; (void)ws_size;
  const void* titles = d_in[0];
  const void* ent    = d_in[1];
  const void* rel    = d_in[2];
  const void* Wnc1 = d_in[3];  const void* bnc1 = d_in[4];
  const void* Wnc2 = d_in[5];  const void* bnc2 = d_in[6];
  const void* Wanc = d_in[7];  const void* banc = d_in[8];
  const void* Waw1 = d_in[9];  const void* baw1 = d_in[10];
  const void* Waw2 = d_in[11]; const void* baw2 = d_in[12];
  const void* Wm1  = d_in[13]; const void* bm1  = d_in[14];
  const void* Wm2  = d_in[15]; const void* bm2  = d_in[16];
  const int* cand  = (const int*)d_in[17];
  const int* clk   = (const int*)d_in[18];
  const int* canda = (const int*)d_in[19];
  const int* clka  = (const int*)d_in[20];
  const int* eadj  = (const int*)d_in[21];
  const int* radj  = (const int*)d_in[22];
  float* ws = (float*)d_ws;

  k_detect<<<1, 256, 0, stream>>>(ent, (int*)d_ws);
  k_prep<<<256, 256, 0, stream>>>(Wnc1, bnc1, Wnc2, bnc2, Wanc, banc, Waw1, baw1,
                                  Waw2, baw2, Wm1, bm1, Wm2, bm2, rel, ws);
  k_news<<<NNEWS / 8, 128, 0, stream>>>(titles, cand, clk, ws);
  k_gather<<<NANCH / 8, 256, 0, stream>>>(ent, canda, clka, eadj, radj, ws);
  k_anchor<<<NNEWS / 8, 256, 0, stream>>>(ws);
  k_mlp<<<NNEWS / 16, 256, 0, stream>>>(ws);
  k_score<<<B_, 128, 0, stream>>>(ws, d_out);
}

// Round 10
// 230.434 us; speedup vs baseline: 1.0737x; 1.0737x over previous
//
#include <hip/hip_runtime.h>
#include <hip/hip_bf16.h>

// ---------------------------------------------------------------------------
// Recommender pipeline.
//  K0 detect : bf16-vs-f32 flag in ws[0]
//  K1 prep   : weights -> ws; K-PACKED f32 for news/mlp GEMMs; Wanc/Waw1
//              SPLIT-BF16 packed [kt][n][32k] hi/lo for 16x16x32 MFMA.
//  K2 news   : news_e = tanh(elu(title@W1^T+b)@W2^T+b)        [3520,128]
//  K3+K4 FUSED k_anchor: R9 post-mortem: memory system saturates at
//              ~2.8 TB/s regardless of occupancy (R8 2.83, R9 2.74 at
//              +33% occ) -> only byte reduction helps. The X materialize
//              round-trip (88MB write + 43MB read) exists only because
//              gather and GEMM were separate. R10 fuses: block = 4 news =
//              80 anchors; ids cached in LDS; 5 chunks of 16 rows:
//              {gather -> split-bf16 -> LDS Xb[16][264] (pad: write free,
//              A-frag ds_read_b128 at bank floor)} -> mfma_16x16x32 3-term
//              split-bf16. H in LDS [80][136]. LDS 67KB -> 2 blocks/CU,
//              cross-block gather/MFMA overlap. X region + k_gather gone.
//  K5 mlp    : elu(elu([news_e,AE]@Wm1^T+b)@Wm2^T+b)          [3520,128]
//  K6 score  : user mean + dot                                 [64,5]
// ---------------------------------------------------------------------------

#define B_ 64
#define S_ 5
#define UC_ 50
#define A_ 20
#define NCAND 320
#define NCLK 3200
#define NNEWS 3520
#define NANCH 70400

// ws layout (float indices)
static constexpr long OFF_WNC1P = 64;        // [192][128][4] f32
static constexpr long OFF_BNC1  = 98368;
static constexpr long OFF_WNC2P = 98496;     // [32][128][4] f32
static constexpr long OFF_BNC2  = 114880;
static constexpr long OFF_WANCP = 115008;    // [8kt][128n][32k] bf16 hi + lo (65536 ushort)
static constexpr long OFF_BANC  = 147776;
static constexpr long OFF_WAW1P = 147904;    // [4kt][128n][32k] bf16 hi + lo (32768 ushort)
static constexpr long OFF_BAW1  = 164288;
static constexpr long OFF_WAW2  = 164416;    // [128]
static constexpr long OFF_BAW2  = 164544;    // [1]
static constexpr long OFF_WM1P  = 164548;    // [64][128][4] f32
static constexpr long OFF_BM1   = 197316;
static constexpr long OFF_WM2P  = 197444;    // [32][128][4] f32
static constexpr long OFF_BM2   = 213828;
static constexpr long OFF_REL   = 213956;    // [100][128] f32
static constexpr long OFF_AE    = 226756;    // [3520][128] f32
static constexpr long OFF_NE    = 677316;    // [3520][128] f32
static constexpr long OFF_MO    = 1127876;   // [3520][128] f32
// (former OFF_X region now unused)

typedef __attribute__((ext_vector_type(8))) short short8v;   // 8 bf16 = 4 VGPR
typedef __attribute__((ext_vector_type(4))) float f32x4;     // MFMA 16x16 acc

__device__ __forceinline__ float ldf(const void* p, long i, int bf) {
  if (bf) {
    unsigned int u = (unsigned int)((const unsigned short*)p)[i];
    u <<= 16;
    return __uint_as_float(u);
  }
  return ((const float*)p)[i];
}

// 4 consecutive elems starting at i (i % 4 == 0)
__device__ __forceinline__ float4 ldf4(const void* p, long i, int bf) {
  float4 f;
  if (bf) {
    const unsigned short* q = (const unsigned short*)p + i;
    uint2 u = *(const uint2*)q;
    f.x = __uint_as_float(u.x << 16);
    f.y = __uint_as_float(u.x & 0xffff0000u);
    f.z = __uint_as_float(u.y << 16);
    f.w = __uint_as_float(u.y & 0xffff0000u);
  } else {
    f = *(const float4*)((const float*)p + i);
  }
  return f;
}

__device__ __forceinline__ float eluf(float v) { return v > 0.f ? v : expm1f(v); }

// split f32 v into hi (truncated bf16 bits) + lo (RNE bf16 of remainder)
__device__ __forceinline__ void splitbf(float v, unsigned short& hi, unsigned short& lo) {
  unsigned int b = __float_as_uint(v);
  hi = (unsigned short)(b >> 16);
  float rm = v - __uint_as_float(b & 0xffff0000u);
  unsigned int rb = __float_as_uint(rm);
  lo = (unsigned short)((rb + 0x7fffu + ((rb >> 16) & 1u)) >> 16);
}

__device__ __forceinline__ float bfh(unsigned short u) {
  return __uint_as_float((unsigned int)u << 16);
}

// ---- K0: dtype detect -----------------------------------------------------
__global__ void k_detect(const void* ent, int* flag) {
  __shared__ int cnt;
  if (threadIdx.x == 0) cnt = 0;
  __syncthreads();
  unsigned short u = ((const unsigned short*)ent)[threadIdx.x];
  int e = (u >> 7) & 0xFF;
  int ok = (e >= 107 && e <= 146) ? 1 : 0;
  atomicAdd(&cnt, ok);
  __syncthreads();
  if (threadIdx.x == 0) *flag = (cnt >= 200) ? 1 : 0;
}

// ---- K1: convert weights --------------------------------------------------
// MD 0: plain f32. MD 2: f32 K-packed [k/4][128][4]. MD 3: split-bf16 MFMA
// B pack [kt][n][32k] hi then lo (for 16x16x32: lane col=l&15, k=(l>>4)*8).
__global__ __launch_bounds__(256) void k_prep(
    const void* s0, const void* s1, const void* s2, const void* s3,
    const void* s4, const void* s5, const void* s6, const void* s7,
    const void* s8, const void* s9, const void* s10, const void* s11,
    const void* s12, const void* s13, const void* s14, float* ws) {
  const int bf = ((const int*)ws)[0];
  const void* srcs[15] = {s0,s1,s2,s3,s4,s5,s6,s7,s8,s9,s10,s11,s12,s13,s14};
  const int R[15] = {128,128,128,128,128,128,128,128,1,  1,  128,128,128,128,100};
  const int C[15] = {768,1,  128,1,  256,1,  128,1,  128,1,  256,1,  128,1,  128};
  const int MD[15]= {2,  0,  2,  0,  3,  0,  3,  0,  0,  0,  2,  0,  2,  0,  0};
  const long OFF[15] = {OFF_WNC1P,OFF_BNC1,OFF_WNC2P,OFF_BNC2,OFF_WANCP,OFF_BANC,
                        OFF_WAW1P,OFF_BAW1,OFF_WAW2,OFF_BAW2,OFF_WM1P,OFF_BM1,
                        OFF_WM2P,OFF_BM2,OFF_REL};
  const long total = 226689;
  for (long idx = (long)blockIdx.x * blockDim.x + threadIdx.x; idx < total;
       idx += (long)gridDim.x * blockDim.x) {
    long rem = idx;
    int s = 0;
    while (rem >= (long)R[s] * C[s]) { rem -= (long)R[s] * C[s]; s++; }
    float v = ldf(srcs[s], rem, bf);
    if (MD[s] == 2) {
      long r = rem / C[s], c = rem - r * C[s];
      ws[OFF[s] + (c >> 2) * 512 + r * 4 + (c & 3)] = v;
    } else if (MD[s] == 3) {
      long r = rem / C[s], c = rem - r * C[s];   // r = out n, c = k
      unsigned short hi, lo;
      splitbf(v, hi, lo);
      unsigned short* H = (unsigned short*)(ws + OFF[s]);
      unsigned short* L = H + (s == 4 ? 32768 : 16384);
      long id2 = ((c >> 5) * 128 + r) * 32 + (c & 31);
      H[id2] = hi;
      L[id2] = lo;
    } else {
      ws[OFF[s] + rem] = v;
    }
  }
}

// ---- K2: news title MLP (128 thr, 8 rows, acc[8]) ------------------------
__global__ __launch_bounds__(128) void k_news(const void* titles, const int* cand,
                                              const int* clk, float* ws) {
  const int bf = ((const int*)ws)[0];
  __shared__ __align__(16) float t[8][768];
  __shared__ __align__(16) float h1[8][128];
  int tid = threadIdx.x;
  long r0 = (long)blockIdx.x * 8;
  for (int x = tid * 4; x < 8 * 768; x += 128 * 4) {
    int c = x / 768, k = x - c * 768;
    long i = r0 + c;
    int id = (i < NCAND) ? cand[i] : clk[i - NCAND];
    *(float4*)&t[c][k] = ldf4(titles, (long)id * 768 + k, bf);
  }
  __syncthreads();
  int j = tid;
  const float4* W1 = (const float4*)(ws + OFF_WNC1P);
  float acc[8];
#pragma unroll
  for (int c = 0; c < 8; c++) acc[c] = 0.f;
  for (int k4 = 0; k4 < 192; k4++) {
    float4 w = W1[k4 * 128 + j];
#pragma unroll
    for (int c = 0; c < 8; c++) {
      const float4 xv = *(const float4*)&t[c][k4 * 4];
      acc[c] += w.x * xv.x + w.y * xv.y + w.z * xv.z + w.w * xv.w;
    }
  }
  float b1 = ws[OFF_BNC1 + j];
#pragma unroll
  for (int c = 0; c < 8; c++) h1[c][j] = eluf(acc[c] + b1);
  __syncthreads();
  const float4* W2 = (const float4*)(ws + OFF_WNC2P);
  float a2[8];
#pragma unroll
  for (int c = 0; c < 8; c++) a2[c] = 0.f;
  for (int k4 = 0; k4 < 32; k4++) {
    float4 w = W2[k4 * 128 + j];
#pragma unroll
    for (int c = 0; c < 8; c++) {
      const float4 xv = *(const float4*)&h1[c][k4 * 4];
      a2[c] += w.x * xv.x + w.y * xv.y + w.z * xv.z + w.w * xv.w;
    }
  }
  float b2 = ws[OFF_BNC2 + j];
  float* NE = ws + OFF_NE;
#pragma unroll
  for (int c = 0; c < 8; c++) NE[(r0 + c) * 128 + j] = tanhf(a2[c] + b2);
}

// ---- K3+K4 FUSED: gather + MFMA anchor GEMMs + softmax --------------------
// block = 4 news = 80 anchor rows, grid 880, 256 thr = 4 waves.
// Per 16-row chunk: gather (32-lane group per row, ids from LDS) ->
// split-bf16 -> Xb[16][264] -> stage-B 16x16x32 MFMA (wave w = cols
// w*32..+31 as 2 N-tiles). H kept split in LDS [80][136]. Stage C same
// shape over K=128. Frag maps (m89): A row=l&15,k=(l>>4)*8; D col=l&15,
// row=(l>>4)*4+j.
__global__ __launch_bounds__(256, 2) void k_anchor(const void* ent, const int* canda,
                                                   const int* clka, const int* eadj,
                                                   const int* radj, float* ws) {
  __shared__ __align__(16) unsigned short XbH[16][264];   // 8.25 KB
  __shared__ __align__(16) unsigned short XbL[16][264];   // 8.25 KB
  __shared__ __align__(16) unsigned short Hhi[80][136];   // 21.25 KB
  __shared__ __align__(16) unsigned short Hlo[80][136];   // 21.25 KB
  __shared__ int NodeIdL[80];
  __shared__ int EAdjL[800];
  __shared__ int RAdjL[800];
  __shared__ float LGp[4][80];

  const int bf = ((const int*)ws)[0];
  int tid = threadIdx.x;
  int lane = tid & 63, wv = tid >> 6;
  int r16 = lane & 15, khh = lane >> 4;       // MFMA frag coords
  int lane32 = tid & 31, grp = tid >> 5;      // gather coords
  const float* relf = ws + OFF_REL;

  const unsigned short* WAH = (const unsigned short*)(ws + OFF_WANCP);
  const unsigned short* WAL = WAH + 32768;
  const unsigned short* W1H = (const unsigned short*)(ws + OFF_WAW1P);
  const unsigned short* W1L = W1H + 16384;

  // --- Prologue: cache node + adjacency ids in LDS ---
  if (tid < 80) {
    long n = (long)blockIdx.x * 80 + tid;
    NodeIdL[tid] = (n < (long)NCAND * A_) ? canda[n] : clka[n - (long)NCAND * A_];
  }
  __syncthreads();
  for (int t = tid; t < 800; t += 256) {
    int rr = t / 10, kk = t - rr * 10;
    int nd = NodeIdL[rr];
    EAdjL[t] = eadj[(long)nd * 10 + kk];
    RAdjL[t] = radj[(long)nd * 10 + kk];
  }
  __syncthreads();

  // --- 5 chunks of 16 rows: gather -> Xb -> stage-B MFMA -> H ---
  for (int mt = 0; mt < 5; ++mt) {
    // gather: 8 groups x 2 rows
    for (int i = 0; i < 2; ++i) {
      int cr = grp * 2 + i;            // chunk row 0..15
      int gr = mt * 16 + cr;           // block row 0..79
      int node = NodeIdL[gr];
      float4 x1 = ldf4(ent, (long)node * 128 + lane32 * 4, bf);
      float4 a = {0.f, 0.f, 0.f, 0.f};
#pragma unroll
      for (int k = 0; k < 10; ++k) {
        int an = EAdjL[gr * 10 + k], rn = RAdjL[gr * 10 + k];
        float4 e = ldf4(ent, (long)an * 128 + lane32 * 4, bf);
        const float4 r = *(const float4*)&relf[(long)rn * 128 + lane32 * 4];
        a.x += e.x + r.x;
        a.y += e.y + r.y;
        a.z += e.z + r.z;
        a.w += e.w + r.w;
      }
      ushort4 h4, l4;
      splitbf(x1.x, h4.x, l4.x); splitbf(x1.y, h4.y, l4.y);
      splitbf(x1.z, h4.z, l4.z); splitbf(x1.w, h4.w, l4.w);
      *(ushort4*)&XbH[cr][lane32 * 4] = h4;
      *(ushort4*)&XbL[cr][lane32 * 4] = l4;
      splitbf(a.x, h4.x, l4.x); splitbf(a.y, h4.y, l4.y);
      splitbf(a.z, h4.z, l4.z); splitbf(a.w, h4.w, l4.w);
      *(ushort4*)&XbH[cr][128 + lane32 * 4] = h4;
      *(ushort4*)&XbL[cr][128 + lane32 * 4] = l4;
    }
    __syncthreads();

    // stage-B MFMA for this chunk: [16 x 256] @ [256 -> 128]
    {
      f32x4 acc0 = {}, acc1 = {};
      int n0 = wv * 32 + r16, n1 = n0 + 16;
      for (int kt = 0; kt < 8; ++kt) {
        short8v ahi = *(const short8v*)&XbH[r16][kt * 32 + khh * 8];
        short8v alo = *(const short8v*)&XbL[r16][kt * 32 + khh * 8];
        long w0 = ((long)(kt * 128 + n0)) * 32 + khh * 8;
        long w1 = ((long)(kt * 128 + n1)) * 32 + khh * 8;
        short8v b0h = *(const short8v*)(WAH + w0);
        short8v b0l = *(const short8v*)(WAL + w0);
        short8v b1h = *(const short8v*)(WAH + w1);
        short8v b1l = *(const short8v*)(WAL + w1);
        acc0 = __builtin_amdgcn_mfma_f32_16x16x32_bf16(ahi, b0h, acc0, 0, 0, 0);
        acc0 = __builtin_amdgcn_mfma_f32_16x16x32_bf16(ahi, b0l, acc0, 0, 0, 0);
        acc0 = __builtin_amdgcn_mfma_f32_16x16x32_bf16(alo, b0h, acc0, 0, 0, 0);
        acc1 = __builtin_amdgcn_mfma_f32_16x16x32_bf16(ahi, b1h, acc1, 0, 0, 0);
        acc1 = __builtin_amdgcn_mfma_f32_16x16x32_bf16(ahi, b1l, acc1, 0, 0, 0);
        acc1 = __builtin_amdgcn_mfma_f32_16x16x32_bf16(alo, b1h, acc1, 0, 0, 0);
      }
      float bc0 = ws[OFF_BANC + n0], bc1 = ws[OFF_BANC + n1];
#pragma unroll
      for (int j = 0; j < 4; ++j) {
        int r = mt * 16 + khh * 4 + j;
        unsigned short hi, lo;
        float h0 = tanhf(acc0[j] + bc0);
        splitbf(h0, hi, lo);
        Hhi[r][n0] = hi; Hlo[r][n0] = lo;
        float h1 = tanhf(acc1[j] + bc1);
        splitbf(h1, hi, lo);
        Hhi[r][n1] = hi; Hlo[r][n1] = lo;
      }
    }
    __syncthreads();
  }

  // --- Stage C: logits = elu(H@Waw1^T+b1)@w2 + b2, [80,128]@[128->128] ---
  {
    int n0 = wv * 32 + r16, n1 = n0 + 16;
    float b10 = ws[OFF_BAW1 + n0], b11 = ws[OFF_BAW1 + n1];
    float w20 = ws[OFF_WAW2 + n0], w21 = ws[OFF_WAW2 + n1];
    for (int mt = 0; mt < 5; ++mt) {
      f32x4 ac0 = {}, ac1 = {};
      for (int kt = 0; kt < 4; ++kt) {
        short8v ahi = *(const short8v*)&Hhi[mt * 16 + r16][kt * 32 + khh * 8];
        short8v alo = *(const short8v*)&Hlo[mt * 16 + r16][kt * 32 + khh * 8];
        long w0 = ((long)(kt * 128 + n0)) * 32 + khh * 8;
        long w1 = ((long)(kt * 128 + n1)) * 32 + khh * 8;
        short8v b0h = *(const short8v*)(W1H + w0);
        short8v b0l = *(const short8v*)(W1L + w0);
        short8v b1h = *(const short8v*)(W1H + w1);
        short8v b1l = *(const short8v*)(W1L + w1);
        ac0 = __builtin_amdgcn_mfma_f32_16x16x32_bf16(ahi, b0h, ac0, 0, 0, 0);
        ac0 = __builtin_amdgcn_mfma_f32_16x16x32_bf16(ahi, b0l, ac0, 0, 0, 0);
        ac0 = __builtin_amdgcn_mfma_f32_16x16x32_bf16(alo, b0h, ac0, 0, 0, 0);
        ac1 = __builtin_amdgcn_mfma_f32_16x16x32_bf16(ahi, b1h, ac1, 0, 0, 0);
        ac1 = __builtin_amdgcn_mfma_f32_16x16x32_bf16(ahi, b1l, ac1, 0, 0, 0);
        ac1 = __builtin_amdgcn_mfma_f32_16x16x32_bf16(alo, b1h, ac1, 0, 0, 0);
      }
#pragma unroll
      for (int j = 0; j < 4; ++j) {
        float v = eluf(ac0[j] + b10) * w20 + eluf(ac1[j] + b11) * w21;
        v += __shfl_xor(v, 1);
        v += __shfl_xor(v, 2);
        v += __shfl_xor(v, 4);
        v += __shfl_xor(v, 8);
        if (r16 == 0) LGp[wv][mt * 16 + khh * 4 + j] = v;
      }
    }
  }
  __syncthreads();

  // --- Stage D: per-news softmax over 20 anchors + weighted sum ---
  {
    int g = tid >> 6, ar = g * 20;   // news 0..3, 64 lanes each
    float bw2 = ws[OFF_BAW2];
    float e[20], mx = -1e30f;
#pragma unroll
    for (int a = 0; a < 20; ++a) {
      int rr = ar + a;
      e[a] = LGp[0][rr] + LGp[1][rr] + LGp[2][rr] + LGp[3][rr] + bw2;
      mx = fmaxf(mx, e[a]);
    }
    float s = 0.f;
#pragma unroll
    for (int a = 0; a < 20; ++a) { e[a] = expf(e[a] - mx); s += e[a]; }
    float inv = 1.0f / s;
    float o0 = 0.f, o1 = 0.f;
#pragma unroll
    for (int a = 0; a < 20; ++a) {
      int rr = ar + a;
      float w = e[a];
      o0 += w * (bfh(Hhi[rr][lane]) + bfh(Hlo[rr][lane]));
      o1 += w * (bfh(Hhi[rr][lane + 64]) + bfh(Hlo[rr][lane + 64]));
    }
    float* AE = ws + OFF_AE;
    long ro = ((long)blockIdx.x * 4 + g) * 128;
    AE[ro + lane]      = o0 * inv;
    AE[ro + lane + 64] = o1 * inv;
  }
}

// ---- K5: final MLP --------------------------------------------------------
__global__ __launch_bounds__(256) void k_mlp(float* ws) {
  __shared__ __align__(16) float xt[16][256];
  __shared__ __align__(16) float h1[16][128];
  int tid = threadIdx.x;
  long r0 = (long)blockIdx.x * 16;
  const float* NE = ws + OFF_NE;
  const float* AE = ws + OFF_AE;
  for (int x = tid; x < 16 * 256; x += 256) {
    int c = x >> 8, k = x & 255;
    xt[c][k] = (k < 128) ? NE[(r0 + c) * 128 + k] : AE[(r0 + c) * 128 + (k - 128)];
  }
  __syncthreads();
  int j = tid & 127, half = tid >> 7;
  const float4* W1 = (const float4*)(ws + OFF_WM1P);
  float acc[8];
#pragma unroll
  for (int c = 0; c < 8; c++) acc[c] = 0.f;
  for (int k4 = 0; k4 < 64; k4++) {
    float4 w = W1[k4 * 128 + j];
#pragma unroll
    for (int c = 0; c < 8; c++) {
      const float4 xv = *(const float4*)&xt[half * 8 + c][k4 * 4];
      acc[c] += w.x * xv.x + w.y * xv.y + w.z * xv.z + w.w * xv.w;
    }
  }
  float b1 = ws[OFF_BM1 + j];
#pragma unroll
  for (int c = 0; c < 8; c++) h1[half * 8 + c][j] = eluf(acc[c] + b1);
  __syncthreads();
  const float4* W2 = (const float4*)(ws + OFF_WM2P);
  float a2[8];
#pragma unroll
  for (int c = 0; c < 8; c++) a2[c] = 0.f;
  for (int k4 = 0; k4 < 32; k4++) {
    float4 w = W2[k4 * 128 + j];
#pragma unroll
    for (int c = 0; c < 8; c++) {
      const float4 xv = *(const float4*)&h1[half * 8 + c][k4 * 4];
      a2[c] += w.x * xv.x + w.y * xv.y + w.z * xv.z + w.w * xv.w;
    }
  }
  float b2 = ws[OFF_BM2 + j];
  float* MO = ws + OFF_MO;
#pragma unroll
  for (int c = 0; c < 8; c++) MO[(r0 + half * 8 + c) * 128 + j] = eluf(a2[c] + b2);
}

// ---- K6: user mean + scores ----------------------------------------------
__global__ __launch_bounds__(128) void k_score(const float* ws, void* out) {
  const int bf = ((const int*)ws)[0];
  int b = blockIdx.x;
  int d = threadIdx.x;
  const float* MO = ws + OFF_MO;
  float u = 0.f;
  for (int t = 0; t < UC_; t++) u += MO[(long)(NCAND + b * UC_ + t) * 128 + d];
  u *= (1.0f / UC_);
  __shared__ float red[2];
  for (int s = 0; s < S_; s++) {
    float p = MO[(long)(b * S_ + s) * 128 + d] * u;
#pragma unroll
    for (int o = 32; o > 0; o >>= 1) p += __shfl_down(p, o, 64);
    if ((d & 63) == 0) red[d >> 6] = p;
    __syncthreads();
    if (d == 0) {
      float v = red[0] + red[1];
      if (bf)
        ((__hip_bfloat16*)out)[b * S_ + s] = __float2bfloat16(v);
      else
        ((float*)out)[b * S_ + s] = v;
    }
    __syncthreads();
  }
}

extern "C" void kernel_launch(void* const* d_in, const int* in_sizes, int n_in,
                              void* d_out, int out_size, void* d_ws, size_t ws_size,
                              hipStream_t stream) {
  (void)in_sizes; (void)n_in; (void)out_size; (void)ws_size;
  const void* titles = d_in[0];
  const void* ent    = d_in[1];
  const void* rel    = d_in[2];
  const void* Wnc1 = d_in[3];  const void* bnc1 = d_in[4];
  const void* Wnc2 = d_in[5];  const void* bnc2 = d_in[6];
  const void* Wanc = d_in[7];  const void* banc = d_in[8];
  const void* Waw1 = d_in[9];  const void* baw1 = d_in[10];
  const void* Waw2 = d_in[11]; const void* baw2 = d_in[12];
  const void* Wm1  = d_in[13]; const void* bm1  = d_in[14];
  const void* Wm2  = d_in[15]; const void* bm2  = d_in[16];
  const int* cand  = (const int*)d_in[17];
  const int* clk   = (const int*)d_in[18];
  const int* canda = (const int*)d_in[19];
  const int* clka  = (const int*)d_in[20];
  const int* eadj  = (const int*)d_in[21];
  const int* radj  = (const int*)d_in[22];
  float* ws = (float*)d_ws;

  k_detect<<<1, 256, 0, stream>>>(ent, (int*)d_ws);
  k_prep<<<256, 256, 0, stream>>>(Wnc1, bnc1, Wnc2, bnc2, Wanc, banc, Waw1, baw1,
                                  Waw2, baw2, Wm1, bm1, Wm2, bm2, rel, ws);
  k_news<<<NNEWS / 8, 128, 0, stream>>>(titles, cand, clk, ws);
  k_anchor<<<NANCH / 80, 256, 0, stream>>>(ent, canda, clka, eadj, radj, ws);
  k_mlp<<<NNEWS / 16, 256, 0, stream>>>(ws);
  k_score<<<B_, 128, 0, stream>>>(ws, d_out);
}

// Round 11
// 224.209 us; speedup vs baseline: 1.1035x; 1.0278x over previous
//
#include <hip/hip_runtime.h>
#include <hip/hip_bf16.h>

// ---------------------------------------------------------------------------
// Recommender pipeline.
//  K0 detect : bf16-vs-f32 flag in ws[0]
//  K1 prep   : weights -> ws; K-PACKED f32 for news/mlp GEMMs; Wanc/Waw1
//              SPLIT-BF16 packed [kt][n][32k] hi/lo for 16x16x32 MFMA.
//  K2 news   : news_e = tanh(elu(title@W1^T+b)@W2^T+b)        [3520,128]
//  K3+K4 FUSED k_anchor (R11): R10 post-mortem: fused kernel ran at only
//              1.37 TB/s vs the 2.8 TB/s this access mix sustains (R8/R9) --
//              per-chunk {gather->barrier->MFMA->barrier} serialized latency
//              against compute with only 2 blocks/CU to cross-overlap.
//              R11: 1 news per block (grid 3520), 20 rows padded to 32
//              (2 M-tiles; pad rows garbage, discarded -- MFMA rows are
//              independent). ONE gather phase -> ONE barrier -> MFMA.
//              kt-outer/mt-inner halves weight L2 traffic. LDS 53.2KB ->
//              3 blocks/CU; 3520 staggered blocks overlap gather vs MFMA.
//              Math order identical to R10 -> bitwise-identical output.
//  K5 mlp    : elu(elu([news_e,AE]@Wm1^T+b)@Wm2^T+b)          [3520,128]
//  K6 score  : user mean + dot                                 [64,5]
// ---------------------------------------------------------------------------

#define B_ 64
#define S_ 5
#define UC_ 50
#define A_ 20
#define NCAND 320
#define NCLK 3200
#define NNEWS 3520
#define NANCH 70400

// ws layout (float indices)
static constexpr long OFF_WNC1P = 64;        // [192][128][4] f32
static constexpr long OFF_BNC1  = 98368;
static constexpr long OFF_WNC2P = 98496;     // [32][128][4] f32
static constexpr long OFF_BNC2  = 114880;
static constexpr long OFF_WANCP = 115008;    // [8kt][128n][32k] bf16 hi + lo (65536 ushort)
static constexpr long OFF_BANC  = 147776;
static constexpr long OFF_WAW1P = 147904;    // [4kt][128n][32k] bf16 hi + lo (32768 ushort)
static constexpr long OFF_BAW1  = 164288;
static constexpr long OFF_WAW2  = 164416;    // [128]
static constexpr long OFF_BAW2  = 164544;    // [1]
static constexpr long OFF_WM1P  = 164548;    // [64][128][4] f32
static constexpr long OFF_BM1   = 197316;
static constexpr long OFF_WM2P  = 197444;    // [32][128][4] f32
static constexpr long OFF_BM2   = 213828;
static constexpr long OFF_REL   = 213956;    // [100][128] f32
static constexpr long OFF_AE    = 226756;    // [3520][128] f32
static constexpr long OFF_NE    = 677316;    // [3520][128] f32
static constexpr long OFF_MO    = 1127876;   // [3520][128] f32

typedef __attribute__((ext_vector_type(8))) short short8v;   // 8 bf16 = 4 VGPR
typedef __attribute__((ext_vector_type(4))) float f32x4;     // MFMA 16x16 acc

__device__ __forceinline__ float ldf(const void* p, long i, int bf) {
  if (bf) {
    unsigned int u = (unsigned int)((const unsigned short*)p)[i];
    u <<= 16;
    return __uint_as_float(u);
  }
  return ((const float*)p)[i];
}

// 4 consecutive elems starting at i (i % 4 == 0)
__device__ __forceinline__ float4 ldf4(const void* p, long i, int bf) {
  float4 f;
  if (bf) {
    const unsigned short* q = (const unsigned short*)p + i;
    uint2 u = *(const uint2*)q;
    f.x = __uint_as_float(u.x << 16);
    f.y = __uint_as_float(u.x & 0xffff0000u);
    f.z = __uint_as_float(u.y << 16);
    f.w = __uint_as_float(u.y & 0xffff0000u);
  } else {
    f = *(const float4*)((const float*)p + i);
  }
  return f;
}

__device__ __forceinline__ float eluf(float v) { return v > 0.f ? v : expm1f(v); }

// split f32 v into hi (truncated bf16 bits) + lo (RNE bf16 of remainder)
__device__ __forceinline__ void splitbf(float v, unsigned short& hi, unsigned short& lo) {
  unsigned int b = __float_as_uint(v);
  hi = (unsigned short)(b >> 16);
  float rm = v - __uint_as_float(b & 0xffff0000u);
  unsigned int rb = __float_as_uint(rm);
  lo = (unsigned short)((rb + 0x7fffu + ((rb >> 16) & 1u)) >> 16);
}

__device__ __forceinline__ float bfh(unsigned short u) {
  return __uint_as_float((unsigned int)u << 16);
}

// ---- K0: dtype detect -----------------------------------------------------
__global__ void k_detect(const void* ent, int* flag) {
  __shared__ int cnt;
  if (threadIdx.x == 0) cnt = 0;
  __syncthreads();
  unsigned short u = ((const unsigned short*)ent)[threadIdx.x];
  int e = (u >> 7) & 0xFF;
  int ok = (e >= 107 && e <= 146) ? 1 : 0;
  atomicAdd(&cnt, ok);
  __syncthreads();
  if (threadIdx.x == 0) *flag = (cnt >= 200) ? 1 : 0;
}

// ---- K1: convert weights --------------------------------------------------
// MD 0: plain f32. MD 2: f32 K-packed [k/4][128][4]. MD 3: split-bf16 MFMA
// B pack [kt][n][32k] hi then lo (for 16x16x32: lane col=l&15, k=(l>>4)*8).
__global__ __launch_bounds__(256) void k_prep(
    const void* s0, const void* s1, const void* s2, const void* s3,
    const void* s4, const void* s5, const void* s6, const void* s7,
    const void* s8, const void* s9, const void* s10, const void* s11,
    const void* s12, const void* s13, const void* s14, float* ws) {
  const int bf = ((const int*)ws)[0];
  const void* srcs[15] = {s0,s1,s2,s3,s4,s5,s6,s7,s8,s9,s10,s11,s12,s13,s14};
  const int R[15] = {128,128,128,128,128,128,128,128,1,  1,  128,128,128,128,100};
  const int C[15] = {768,1,  128,1,  256,1,  128,1,  128,1,  256,1,  128,1,  128};
  const int MD[15]= {2,  0,  2,  0,  3,  0,  3,  0,  0,  0,  2,  0,  2,  0,  0};
  const long OFF[15] = {OFF_WNC1P,OFF_BNC1,OFF_WNC2P,OFF_BNC2,OFF_WANCP,OFF_BANC,
                        OFF_WAW1P,OFF_BAW1,OFF_WAW2,OFF_BAW2,OFF_WM1P,OFF_BM1,
                        OFF_WM2P,OFF_BM2,OFF_REL};
  const long total = 226689;
  for (long idx = (long)blockIdx.x * blockDim.x + threadIdx.x; idx < total;
       idx += (long)gridDim.x * blockDim.x) {
    long rem = idx;
    int s = 0;
    while (rem >= (long)R[s] * C[s]) { rem -= (long)R[s] * C[s]; s++; }
    float v = ldf(srcs[s], rem, bf);
    if (MD[s] == 2) {
      long r = rem / C[s], c = rem - r * C[s];
      ws[OFF[s] + (c >> 2) * 512 + r * 4 + (c & 3)] = v;
    } else if (MD[s] == 3) {
      long r = rem / C[s], c = rem - r * C[s];   // r = out n, c = k
      unsigned short hi, lo;
      splitbf(v, hi, lo);
      unsigned short* H = (unsigned short*)(ws + OFF[s]);
      unsigned short* L = H + (s == 4 ? 32768 : 16384);
      long id2 = ((c >> 5) * 128 + r) * 32 + (c & 31);
      H[id2] = hi;
      L[id2] = lo;
    } else {
      ws[OFF[s] + rem] = v;
    }
  }
}

// ---- K2: news title MLP (128 thr, 8 rows, acc[8]) ------------------------
__global__ __launch_bounds__(128) void k_news(const void* titles, const int* cand,
                                              const int* clk, float* ws) {
  const int bf = ((const int*)ws)[0];
  __shared__ __align__(16) float t[8][768];
  __shared__ __align__(16) float h1[8][128];
  int tid = threadIdx.x;
  long r0 = (long)blockIdx.x * 8;
  for (int x = tid * 4; x < 8 * 768; x += 128 * 4) {
    int c = x / 768, k = x - c * 768;
    long i = r0 + c;
    int id = (i < NCAND) ? cand[i] : clk[i - NCAND];
    *(float4*)&t[c][k] = ldf4(titles, (long)id * 768 + k, bf);
  }
  __syncthreads();
  int j = tid;
  const float4* W1 = (const float4*)(ws + OFF_WNC1P);
  float acc[8];
#pragma unroll
  for (int c = 0; c < 8; c++) acc[c] = 0.f;
  for (int k4 = 0; k4 < 192; k4++) {
    float4 w = W1[k4 * 128 + j];
#pragma unroll
    for (int c = 0; c < 8; c++) {
      const float4 xv = *(const float4*)&t[c][k4 * 4];
      acc[c] += w.x * xv.x + w.y * xv.y + w.z * xv.z + w.w * xv.w;
    }
  }
  float b1 = ws[OFF_BNC1 + j];
#pragma unroll
  for (int c = 0; c < 8; c++) h1[c][j] = eluf(acc[c] + b1);
  __syncthreads();
  const float4* W2 = (const float4*)(ws + OFF_WNC2P);
  float a2[8];
#pragma unroll
  for (int c = 0; c < 8; c++) a2[c] = 0.f;
  for (int k4 = 0; k4 < 32; k4++) {
    float4 w = W2[k4 * 128 + j];
#pragma unroll
    for (int c = 0; c < 8; c++) {
      const float4 xv = *(const float4*)&h1[c][k4 * 4];
      a2[c] += w.x * xv.x + w.y * xv.y + w.z * xv.z + w.w * xv.w;
    }
  }
  float b2 = ws[OFF_BNC2 + j];
  float* NE = ws + OFF_NE;
#pragma unroll
  for (int c = 0; c < 8; c++) NE[(r0 + c) * 128 + j] = tanhf(a2[c] + b2);
}

// ---- K3+K4 FUSED: gather + MFMA anchor GEMMs + softmax --------------------
// block = 1 news = 20 anchor rows (padded to 32), grid 3520, 256 thr = 4
// waves. ONE gather phase (8 groups x <=3 rows, 11 indep 256B loads each)
// -> ONE barrier -> stage-B MFMA (kt-outer: B-frags loaded once, 2 M-tiles
// inner) -> stage C -> softmax. Pad rows (20-31) compute garbage that is
// discarded (MFMA output rows depend only on same A row). Frag maps (m89):
// A row=l&15, k=(l>>4)*8; D col=l&15, row=(l>>4)*4+j.
__global__ __launch_bounds__(256, 3) void k_anchor(const void* ent, const int* canda,
                                                   const int* clka, const int* eadj,
                                                   const int* radj, float* ws) {
  __shared__ __align__(16) unsigned short XbH[32][264];   // 16.5 KB
  __shared__ __align__(16) unsigned short XbL[32][264];   // 16.5 KB
  __shared__ __align__(16) unsigned short Hhi[32][136];   // 8.5 KB
  __shared__ __align__(16) unsigned short Hlo[32][136];   // 8.5 KB
  __shared__ int NodeIdL[20];
  __shared__ int EAdjL[200];
  __shared__ int RAdjL[200];
  __shared__ float LGp[4][20];

  const int bf = ((const int*)ws)[0];
  int tid = threadIdx.x;
  int lane = tid & 63, wv = tid >> 6;
  int r16 = lane & 15, khh = lane >> 4;       // MFMA frag coords
  int lane32 = tid & 31, grp = tid >> 5;      // gather coords
  const float* relf = ws + OFF_REL;

  const unsigned short* WAH = (const unsigned short*)(ws + OFF_WANCP);
  const unsigned short* WAL = WAH + 32768;
  const unsigned short* W1H = (const unsigned short*)(ws + OFF_WAW1P);
  const unsigned short* W1L = W1H + 16384;

  // --- Prologue: cache node + adjacency ids in LDS ---
  if (tid < 20) {
    long n = (long)blockIdx.x * 20 + tid;
    NodeIdL[tid] = (n < (long)NCAND * A_) ? canda[n] : clka[n - (long)NCAND * A_];
  }
  __syncthreads();
  if (tid < 200) {
    int rr = tid / 10, kk = tid - rr * 10;
    int nd = NodeIdL[rr];
    EAdjL[tid] = eadj[(long)nd * 10 + kk];
    RAdjL[tid] = radj[(long)nd * 10 + kk];
  }
  __syncthreads();

  // --- Gather phase: 8 groups, rows grp, grp+8, grp+16 (guard <20) ---
#pragma unroll
  for (int i = 0; i < 3; ++i) {
    int row = grp + i * 8;
    if (row < 20) {
      int node = NodeIdL[row];
      float4 x1 = ldf4(ent, (long)node * 128 + lane32 * 4, bf);
      float4 a = {0.f, 0.f, 0.f, 0.f};
#pragma unroll
      for (int k = 0; k < 10; ++k) {
        int an = EAdjL[row * 10 + k], rn = RAdjL[row * 10 + k];
        float4 e = ldf4(ent, (long)an * 128 + lane32 * 4, bf);
        const float4 r = *(const float4*)&relf[(long)rn * 128 + lane32 * 4];
        a.x += e.x + r.x;
        a.y += e.y + r.y;
        a.z += e.z + r.z;
        a.w += e.w + r.w;
      }
      ushort4 h4, l4;
      splitbf(x1.x, h4.x, l4.x); splitbf(x1.y, h4.y, l4.y);
      splitbf(x1.z, h4.z, l4.z); splitbf(x1.w, h4.w, l4.w);
      *(ushort4*)&XbH[row][lane32 * 4] = h4;
      *(ushort4*)&XbL[row][lane32 * 4] = l4;
      splitbf(a.x, h4.x, l4.x); splitbf(a.y, h4.y, l4.y);
      splitbf(a.z, h4.z, l4.z); splitbf(a.w, h4.w, l4.w);
      *(ushort4*)&XbH[row][128 + lane32 * 4] = h4;
      *(ushort4*)&XbL[row][128 + lane32 * 4] = l4;
    }
  }
  __syncthreads();

  // --- Stage B: H = tanh(X @ Wanc^T + b), [20(pad32) x 256] @ [256->128] ---
  {
    int n0 = wv * 32 + r16, n1 = n0 + 16;
    f32x4 acc[2][2] = {};
    for (int kt = 0; kt < 8; ++kt) {
      long w0 = ((long)(kt * 128 + n0)) * 32 + khh * 8;
      long w1 = ((long)(kt * 128 + n1)) * 32 + khh * 8;
      short8v b0h = *(const short8v*)(WAH + w0);
      short8v b0l = *(const short8v*)(WAL + w0);
      short8v b1h = *(const short8v*)(WAH + w1);
      short8v b1l = *(const short8v*)(WAL + w1);
#pragma unroll
      for (int mt = 0; mt < 2; ++mt) {
        short8v ahi = *(const short8v*)&XbH[mt * 16 + r16][kt * 32 + khh * 8];
        short8v alo = *(const short8v*)&XbL[mt * 16 + r16][kt * 32 + khh * 8];
        acc[mt][0] = __builtin_amdgcn_mfma_f32_16x16x32_bf16(ahi, b0h, acc[mt][0], 0, 0, 0);
        acc[mt][0] = __builtin_amdgcn_mfma_f32_16x16x32_bf16(ahi, b0l, acc[mt][0], 0, 0, 0);
        acc[mt][0] = __builtin_amdgcn_mfma_f32_16x16x32_bf16(alo, b0h, acc[mt][0], 0, 0, 0);
        acc[mt][1] = __builtin_amdgcn_mfma_f32_16x16x32_bf16(ahi, b1h, acc[mt][1], 0, 0, 0);
        acc[mt][1] = __builtin_amdgcn_mfma_f32_16x16x32_bf16(ahi, b1l, acc[mt][1], 0, 0, 0);
        acc[mt][1] = __builtin_amdgcn_mfma_f32_16x16x32_bf16(alo, b1h, acc[mt][1], 0, 0, 0);
      }
    }
    float bc0 = ws[OFF_BANC + n0], bc1 = ws[OFF_BANC + n1];
#pragma unroll
    for (int mt = 0; mt < 2; ++mt)
#pragma unroll
      for (int j = 0; j < 4; ++j) {
        int r = mt * 16 + khh * 4 + j;
        if (r < 20) {
          unsigned short hi, lo;
          float h0 = tanhf(acc[mt][0][j] + bc0);
          splitbf(h0, hi, lo);
          Hhi[r][n0] = hi; Hlo[r][n0] = lo;
          float h1 = tanhf(acc[mt][1][j] + bc1);
          splitbf(h1, hi, lo);
          Hhi[r][n1] = hi; Hlo[r][n1] = lo;
        }
      }
  }
  __syncthreads();

  // --- Stage C: logits = elu(H@Waw1^T+b1)@w2 + b2, [20(pad32)x128]@[128->128] ---
  {
    int n0 = wv * 32 + r16, n1 = n0 + 16;
    float b10 = ws[OFF_BAW1 + n0], b11 = ws[OFF_BAW1 + n1];
    float w20 = ws[OFF_WAW2 + n0], w21 = ws[OFF_WAW2 + n1];
    f32x4 ac[2][2] = {};
    for (int kt = 0; kt < 4; ++kt) {
      long w0 = ((long)(kt * 128 + n0)) * 32 + khh * 8;
      long w1 = ((long)(kt * 128 + n1)) * 32 + khh * 8;
      short8v b0h = *(const short8v*)(W1H + w0);
      short8v b0l = *(const short8v*)(W1L + w0);
      short8v b1h = *(const short8v*)(W1H + w1);
      short8v b1l = *(const short8v*)(W1L + w1);
#pragma unroll
      for (int mt = 0; mt < 2; ++mt) {
        short8v ahi = *(const short8v*)&Hhi[mt * 16 + r16][kt * 32 + khh * 8];
        short8v alo = *(const short8v*)&Hlo[mt * 16 + r16][kt * 32 + khh * 8];
        ac[mt][0] = __builtin_amdgcn_mfma_f32_16x16x32_bf16(ahi, b0h, ac[mt][0], 0, 0, 0);
        ac[mt][0] = __builtin_amdgcn_mfma_f32_16x16x32_bf16(ahi, b0l, ac[mt][0], 0, 0, 0);
        ac[mt][0] = __builtin_amdgcn_mfma_f32_16x16x32_bf16(alo, b0h, ac[mt][0], 0, 0, 0);
        ac[mt][1] = __builtin_amdgcn_mfma_f32_16x16x32_bf16(ahi, b1h, ac[mt][1], 0, 0, 0);
        ac[mt][1] = __builtin_amdgcn_mfma_f32_16x16x32_bf16(ahi, b1l, ac[mt][1], 0, 0, 0);
        ac[mt][1] = __builtin_amdgcn_mfma_f32_16x16x32_bf16(alo, b1h, ac[mt][1], 0, 0, 0);
      }
    }
#pragma unroll
    for (int mt = 0; mt < 2; ++mt)
#pragma unroll
      for (int j = 0; j < 4; ++j) {
        float v = eluf(ac[mt][0][j] + b10) * w20 + eluf(ac[mt][1][j] + b11) * w21;
        v += __shfl_xor(v, 1);
        v += __shfl_xor(v, 2);
        v += __shfl_xor(v, 4);
        v += __shfl_xor(v, 8);
        int r = mt * 16 + khh * 4 + j;
        if (r16 == 0 && r < 20) LGp[wv][r] = v;
      }
  }
  __syncthreads();

  // --- Stage D: softmax over 20 anchors + weighted sum (128 threads) ---
  if (tid < 128) {
    float bw2 = ws[OFF_BAW2];
    float e[20], mx = -1e30f;
#pragma unroll
    for (int a = 0; a < 20; ++a) {
      e[a] = LGp[0][a] + LGp[1][a] + LGp[2][a] + LGp[3][a] + bw2;
      mx = fmaxf(mx, e[a]);
    }
    float s = 0.f;
#pragma unroll
    for (int a = 0; a < 20; ++a) { e[a] = expf(e[a] - mx); s += e[a]; }
    float inv = 1.0f / s;
    float o = 0.f;
#pragma unroll
    for (int a = 0; a < 20; ++a)
      o += e[a] * (bfh(Hhi[a][tid]) + bfh(Hlo[a][tid]));
    float* AE = ws + OFF_AE;
    AE[(long)blockIdx.x * 128 + tid] = o * inv;
  }
}

// ---- K5: final MLP --------------------------------------------------------
__global__ __launch_bounds__(256) void k_mlp(float* ws) {
  __shared__ __align__(16) float xt[16][256];
  __shared__ __align__(16) float h1[16][128];
  int tid = threadIdx.x;
  long r0 = (long)blockIdx.x * 16;
  const float* NE = ws + OFF_NE;
  const float* AE = ws + OFF_AE;
  for (int x = tid; x < 16 * 256; x += 256) {
    int c = x >> 8, k = x & 255;
    xt[c][k] = (k < 128) ? NE[(r0 + c) * 128 + k] : AE[(r0 + c) * 128 + (k - 128)];
  }
  __syncthreads();
  int j = tid & 127, half = tid >> 7;
  const float4* W1 = (const float4*)(ws + OFF_WM1P);
  float acc[8];
#pragma unroll
  for (int c = 0; c < 8; c++) acc[c] = 0.f;
  for (int k4 = 0; k4 < 64; k4++) {
    float4 w = W1[k4 * 128 + j];
#pragma unroll
    for (int c = 0; c < 8; c++) {
      const float4 xv = *(const float4*)&xt[half * 8 + c][k4 * 4];
      acc[c] += w.x * xv.x + w.y * xv.y + w.z * xv.z + w.w * xv.w;
    }
  }
  float b1 = ws[OFF_BM1 + j];
#pragma unroll
  for (int c = 0; c < 8; c++) h1[half * 8 + c][j] = eluf(acc[c] + b1);
  __syncthreads();
  const float4* W2 = (const float4*)(ws + OFF_WM2P);
  float a2[8];
#pragma unroll
  for (int c = 0; c < 8; c++) a2[c] = 0.f;
  for (int k4 = 0; k4 < 32; k4++) {
    float4 w = W2[k4 * 128 + j];
#pragma unroll
    for (int c = 0; c < 8; c++) {
      const float4 xv = *(const float4*)&h1[half * 8 + c][k4 * 4];
      a2[c] += w.x * xv.x + w.y * xv.y + w.z * xv.z + w.w * xv.w;
    }
  }
  float b2 = ws[OFF_BM2 + j];
  float* MO = ws + OFF_MO;
#pragma unroll
  for (int c = 0; c < 8; c++) MO[(r0 + half * 8 + c) * 128 + j] = eluf(a2[c] + b2);
}

// ---- K6: user mean + scores ----------------------------------------------
__global__ __launch_bounds__(128) void k_score(const float* ws, void* out) {
  const int bf = ((const int*)ws)[0];
  int b = blockIdx.x;
  int d = threadIdx.x;
  const float* MO = ws + OFF_MO;
  float u = 0.f;
  for (int t = 0; t < UC_; t++) u += MO[(long)(NCAND + b * UC_ + t) * 128 + d];
  u *= (1.0f / UC_);
  __shared__ float red[2];
  for (int s = 0; s < S_; s++) {
    float p = MO[(long)(b * S_ + s) * 128 + d] * u;
#pragma unroll
    for (int o = 32; o > 0; o >>= 1) p += __shfl_down(p, o, 64);
    if ((d & 63) == 0) red[d >> 6] = p;
    __syncthreads();
    if (d == 0) {
      float v = red[0] + red[1];
      if (bf)
        ((__hip_bfloat16*)out)[b * S_ + s] = __float2bfloat16(v);
      else
        ((float*)out)[b * S_ + s] = v;
    }
    __syncthreads();
  }
}

extern "C" void kernel_launch(void* const* d_in, const int* in_sizes, int n_in,
                              void* d_out, int out_size, void* d_ws, size_t ws_size,
                              hipStream_t stream) {
  (void)in_sizes; (void)n_in; (void)out_size; (void)ws_size;
  const void* titles = d_in[0];
  const void* ent    = d_in[1];
  const void* rel    = d_in[2];
  const void* Wnc1 = d_in[3];  const void* bnc1 = d_in[4];
  const void* Wnc2 = d_in[5];  const void* bnc2 = d_in[6];
  const void* Wanc = d_in[7];  const void* banc = d_in[8];
  const void* Waw1 = d_in[9];  const void* baw1 = d_in[10];
  const void* Waw2 = d_in[11]; const void* baw2 = d_in[12];
  const void* Wm1  = d_in[13]; const void* bm1  = d_in[14];
  const void* Wm2  = d_in[15]; const void* bm2  = d_in[16];
  const int* cand  = (const int*)d_in[17];
  const int* clk   = (const int*)d_in[18];
  const int* canda = (const int*)d_in[19];
  const int* clka  = (const int*)d_in[20];
  const int* eadj  = (const int*)d_in[21];
  const int* radj  = (const int*)d_in[22];
  float* ws = (float*)d_ws;

  k_detect<<<1, 256, 0, stream>>>(ent, (int*)d_ws);
  k_prep<<<256, 256, 0, stream>>>(Wnc1, bnc1, Wnc2, bnc2, Wanc, banc, Waw1, baw1,
                                  Waw2, baw2, Wm1, bm1, Wm2, bm2, rel, ws);
  k_news<<<NNEWS / 8, 128, 0, stream>>>(titles, cand, clk, ws);
  k_anchor<<<NNEWS, 256, 0, stream>>>(ent, canda, clka, eadj, radj, ws);
  k_mlp<<<NNEWS / 16, 256, 0, stream>>>(ws);
  k_score<<<B_, 128, 0, stream>>>(ws, d_out);
}

// Round 12
// 219.865 us; speedup vs baseline: 1.1253x; 1.0198x over previous
//
#include <hip/hip_runtime.h>
#include <hip/hip_bf16.h>

// ---------------------------------------------------------------------------
// Recommender pipeline.
//  K0 detect : bf16-vs-f32 flag in ws[0]
//  K1 prep   : weights -> ws; K-PACKED f32 for news/mlp GEMMs; Wanc/Waw1
//              SPLIT-BF16 packed [kt][n][32k] hi/lo for 16x16x32 MFMA.
//  K2 news   : news_e = tanh(elu(title@W1^T+b)@W2^T+b)        [3520,128]
//  K3+K4 FUSED k_anchor (R12): R11 post-mortem: occupancy 20->30% with
//              ZERO speedup, BW pinned 1.42 TB/s, VGPR=68 -> per-wave
//              gather issue serialized (compiler can't pipeline rows past
//              divergent row<20 guards with 68 regs). R12: bf16 path
//              issues ALL ent-row loads (2-3 rows x 11 = 22-33 uint2)
//              into static reg arrays BEFORE consuming; row counts made
//              wave-uniform (waves 0-1: 3 rows/group, waves 2-3: 2).
//              LDS trimmed to 20 real rows (mt=1 A-reads alias 16+(r16&3);
//              garbage confined to discarded D rows) -> ~34KB -> 4 blk/CU.
//              Consume order identical -> bitwise-identical output.
//  K5 mlp    : elu(elu([news_e,AE]@Wm1^T+b)@Wm2^T+b)          [3520,128]
//  K6 score  : user mean + dot                                 [64,5]
// ---------------------------------------------------------------------------

#define B_ 64
#define S_ 5
#define UC_ 50
#define A_ 20
#define NCAND 320
#define NCLK 3200
#define NNEWS 3520
#define NANCH 70400

// ws layout (float indices)
static constexpr long OFF_WNC1P = 64;        // [192][128][4] f32
static constexpr long OFF_BNC1  = 98368;
static constexpr long OFF_WNC2P = 98496;     // [32][128][4] f32
static constexpr long OFF_BNC2  = 114880;
static constexpr long OFF_WANCP = 115008;    // [8kt][128n][32k] bf16 hi + lo (65536 ushort)
static constexpr long OFF_BANC  = 147776;
static constexpr long OFF_WAW1P = 147904;    // [4kt][128n][32k] bf16 hi + lo (32768 ushort)
static constexpr long OFF_BAW1  = 164288;
static constexpr long OFF_WAW2  = 164416;    // [128]
static constexpr long OFF_BAW2  = 164544;    // [1]
static constexpr long OFF_WM1P  = 164548;    // [64][128][4] f32
static constexpr long OFF_BM1   = 197316;
static constexpr long OFF_WM2P  = 197444;    // [32][128][4] f32
static constexpr long OFF_BM2   = 213828;
static constexpr long OFF_REL   = 213956;    // [100][128] f32
static constexpr long OFF_AE    = 226756;    // [3520][128] f32
static constexpr long OFF_NE    = 677316;    // [3520][128] f32
static constexpr long OFF_MO    = 1127876;   // [3520][128] f32

typedef __attribute__((ext_vector_type(8))) short short8v;   // 8 bf16 = 4 VGPR
typedef __attribute__((ext_vector_type(4))) float f32x4;     // MFMA 16x16 acc

__device__ __forceinline__ float ldf(const void* p, long i, int bf) {
  if (bf) {
    unsigned int u = (unsigned int)((const unsigned short*)p)[i];
    u <<= 16;
    return __uint_as_float(u);
  }
  return ((const float*)p)[i];
}

// 4 consecutive elems starting at i (i % 4 == 0)
__device__ __forceinline__ float4 ldf4(const void* p, long i, int bf) {
  float4 f;
  if (bf) {
    const unsigned short* q = (const unsigned short*)p + i;
    uint2 u = *(const uint2*)q;
    f.x = __uint_as_float(u.x << 16);
    f.y = __uint_as_float(u.x & 0xffff0000u);
    f.z = __uint_as_float(u.y << 16);
    f.w = __uint_as_float(u.y & 0xffff0000u);
  } else {
    f = *(const float4*)((const float*)p + i);
  }
  return f;
}

// bf16 raw uint2 -> float4 (identical bit path to ldf4's bf branch)
__device__ __forceinline__ float4 cvtbf4(uint2 u) {
  float4 f;
  f.x = __uint_as_float(u.x << 16);
  f.y = __uint_as_float(u.x & 0xffff0000u);
  f.z = __uint_as_float(u.y << 16);
  f.w = __uint_as_float(u.y & 0xffff0000u);
  return f;
}

__device__ __forceinline__ float eluf(float v) { return v > 0.f ? v : expm1f(v); }

// split f32 v into hi (truncated bf16 bits) + lo (RNE bf16 of remainder)
__device__ __forceinline__ void splitbf(float v, unsigned short& hi, unsigned short& lo) {
  unsigned int b = __float_as_uint(v);
  hi = (unsigned short)(b >> 16);
  float rm = v - __uint_as_float(b & 0xffff0000u);
  unsigned int rb = __float_as_uint(rm);
  lo = (unsigned short)((rb + 0x7fffu + ((rb >> 16) & 1u)) >> 16);
}

__device__ __forceinline__ float bfh(unsigned short u) {
  return __uint_as_float((unsigned int)u << 16);
}

// ---- K0: dtype detect -----------------------------------------------------
__global__ void k_detect(const void* ent, int* flag) {
  __shared__ int cnt;
  if (threadIdx.x == 0) cnt = 0;
  __syncthreads();
  unsigned short u = ((const unsigned short*)ent)[threadIdx.x];
  int e = (u >> 7) & 0xFF;
  int ok = (e >= 107 && e <= 146) ? 1 : 0;
  atomicAdd(&cnt, ok);
  __syncthreads();
  if (threadIdx.x == 0) *flag = (cnt >= 200) ? 1 : 0;
}

// ---- K1: convert weights --------------------------------------------------
// MD 0: plain f32. MD 2: f32 K-packed [k/4][128][4]. MD 3: split-bf16 MFMA
// B pack [kt][n][32k] hi then lo (for 16x16x32: lane col=l&15, k=(l>>4)*8).
__global__ __launch_bounds__(256) void k_prep(
    const void* s0, const void* s1, const void* s2, const void* s3,
    const void* s4, const void* s5, const void* s6, const void* s7,
    const void* s8, const void* s9, const void* s10, const void* s11,
    const void* s12, const void* s13, const void* s14, float* ws) {
  const int bf = ((const int*)ws)[0];
  const void* srcs[15] = {s0,s1,s2,s3,s4,s5,s6,s7,s8,s9,s10,s11,s12,s13,s14};
  const int R[15] = {128,128,128,128,128,128,128,128,1,  1,  128,128,128,128,100};
  const int C[15] = {768,1,  128,1,  256,1,  128,1,  128,1,  256,1,  128,1,  128};
  const int MD[15]= {2,  0,  2,  0,  3,  0,  3,  0,  0,  0,  2,  0,  2,  0,  0};
  const long OFF[15] = {OFF_WNC1P,OFF_BNC1,OFF_WNC2P,OFF_BNC2,OFF_WANCP,OFF_BANC,
                        OFF_WAW1P,OFF_BAW1,OFF_WAW2,OFF_BAW2,OFF_WM1P,OFF_BM1,
                        OFF_WM2P,OFF_BM2,OFF_REL};
  const long total = 226689;
  for (long idx = (long)blockIdx.x * blockDim.x + threadIdx.x; idx < total;
       idx += (long)gridDim.x * blockDim.x) {
    long rem = idx;
    int s = 0;
    while (rem >= (long)R[s] * C[s]) { rem -= (long)R[s] * C[s]; s++; }
    float v = ldf(srcs[s], rem, bf);
    if (MD[s] == 2) {
      long r = rem / C[s], c = rem - r * C[s];
      ws[OFF[s] + (c >> 2) * 512 + r * 4 + (c & 3)] = v;
    } else if (MD[s] == 3) {
      long r = rem / C[s], c = rem - r * C[s];   // r = out n, c = k
      unsigned short hi, lo;
      splitbf(v, hi, lo);
      unsigned short* H = (unsigned short*)(ws + OFF[s]);
      unsigned short* L = H + (s == 4 ? 32768 : 16384);
      long id2 = ((c >> 5) * 128 + r) * 32 + (c & 31);
      H[id2] = hi;
      L[id2] = lo;
    } else {
      ws[OFF[s] + rem] = v;
    }
  }
}

// ---- K2: news title MLP (128 thr, 8 rows, acc[8]) ------------------------
__global__ __launch_bounds__(128) void k_news(const void* titles, const int* cand,
                                              const int* clk, float* ws) {
  const int bf = ((const int*)ws)[0];
  __shared__ __align__(16) float t[8][768];
  __shared__ __align__(16) float h1[8][128];
  int tid = threadIdx.x;
  long r0 = (long)blockIdx.x * 8;
  for (int x = tid * 4; x < 8 * 768; x += 128 * 4) {
    int c = x / 768, k = x - c * 768;
    long i = r0 + c;
    int id = (i < NCAND) ? cand[i] : clk[i - NCAND];
    *(float4*)&t[c][k] = ldf4(titles, (long)id * 768 + k, bf);
  }
  __syncthreads();
  int j = tid;
  const float4* W1 = (const float4*)(ws + OFF_WNC1P);
  float acc[8];
#pragma unroll
  for (int c = 0; c < 8; c++) acc[c] = 0.f;
  for (int k4 = 0; k4 < 192; k4++) {
    float4 w = W1[k4 * 128 + j];
#pragma unroll
    for (int c = 0; c < 8; c++) {
      const float4 xv = *(const float4*)&t[c][k4 * 4];
      acc[c] += w.x * xv.x + w.y * xv.y + w.z * xv.z + w.w * xv.w;
    }
  }
  float b1 = ws[OFF_BNC1 + j];
#pragma unroll
  for (int c = 0; c < 8; c++) h1[c][j] = eluf(acc[c] + b1);
  __syncthreads();
  const float4* W2 = (const float4*)(ws + OFF_WNC2P);
  float a2[8];
#pragma unroll
  for (int c = 0; c < 8; c++) a2[c] = 0.f;
  for (int k4 = 0; k4 < 32; k4++) {
    float4 w = W2[k4 * 128 + j];
#pragma unroll
    for (int c = 0; c < 8; c++) {
      const float4 xv = *(const float4*)&h1[c][k4 * 4];
      a2[c] += w.x * xv.x + w.y * xv.y + w.z * xv.z + w.w * xv.w;
    }
  }
  float b2 = ws[OFF_BNC2 + j];
  float* NE = ws + OFF_NE;
#pragma unroll
  for (int c = 0; c < 8; c++) NE[(r0 + c) * 128 + j] = tanhf(a2[c] + b2);
}

// ---- K3+K4 FUSED: gather + MFMA anchor GEMMs + softmax --------------------
// block = 1 news = 20 anchor rows, grid 3520, 256 thr = 4 waves.
// Gather: 8 groups; waves 0-1 (groups 0-3) own rows {g, g+8, g+16},
// waves 2-3 (groups 4-7) own rows {g, g+8} -- wave-uniform counts, no
// divergent guards. bf16 path issues ALL 22-33 raw uint2 loads before
// consuming (deep vmcnt pipeline). LDS arrays hold 20 real rows; mt=1
// MFMA A-reads alias row 16+(r16&3) (garbage confined to discarded D
// rows >= 20, since MFMA D row r depends only on A row r). Frag maps
// (m89): A row=l&15, k=(l>>4)*8; D col=l&15, row=(l>>4)*4+j.
__global__ __launch_bounds__(256, 3) void k_anchor(const void* ent, const int* canda,
                                                   const int* clka, const int* eadj,
                                                   const int* radj, float* ws) {
  __shared__ __align__(16) unsigned short XbH[20][264];   // 10.3 KB
  __shared__ __align__(16) unsigned short XbL[20][264];   // 10.3 KB
  __shared__ __align__(16) unsigned short Hhi[20][136];   // 5.3 KB
  __shared__ __align__(16) unsigned short Hlo[20][136];   // 5.3 KB
  __shared__ int NodeIdL[20];
  __shared__ int EAdjL[200];
  __shared__ int RAdjL[200];
  __shared__ float LGp[4][20];

  const int bf = ((const int*)ws)[0];
  int tid = threadIdx.x;
  int lane = tid & 63, wv = tid >> 6;
  int r16 = lane & 15, khh = lane >> 4;       // MFMA frag coords
  int lane32 = tid & 31, grp = tid >> 5;      // gather coords
  const float* relf = ws + OFF_REL;

  const unsigned short* WAH = (const unsigned short*)(ws + OFF_WANCP);
  const unsigned short* WAL = WAH + 32768;
  const unsigned short* W1H = (const unsigned short*)(ws + OFF_WAW1P);
  const unsigned short* W1L = W1H + 16384;

  // --- Prologue: cache node + adjacency ids in LDS ---
  if (tid < 20) {
    long n = (long)blockIdx.x * 20 + tid;
    NodeIdL[tid] = (n < (long)NCAND * A_) ? canda[n] : clka[n - (long)NCAND * A_];
  }
  __syncthreads();
  if (tid < 200) {
    int rr = tid / 10, kk = tid - rr * 10;
    int nd = NodeIdL[rr];
    EAdjL[tid] = eadj[(long)nd * 10 + kk];
    RAdjL[tid] = radj[(long)nd * 10 + kk];
  }
  __syncthreads();

  // --- Gather phase ---
  // consume: convert raw bf16 row-loads, add rel (L2-hot), split, store.
  auto consume = [&](int row, uint2 (&raw)[11]) {
    float4 x1 = cvtbf4(raw[0]);
    float4 a = {0.f, 0.f, 0.f, 0.f};
#pragma unroll
    for (int k = 0; k < 10; ++k) {
      float4 e = cvtbf4(raw[1 + k]);
      const float4 r = *(const float4*)&relf[(long)RAdjL[row * 10 + k] * 128 + lane32 * 4];
      a.x += e.x + r.x;
      a.y += e.y + r.y;
      a.z += e.z + r.z;
      a.w += e.w + r.w;
    }
    ushort4 h4, l4;
    splitbf(x1.x, h4.x, l4.x); splitbf(x1.y, h4.y, l4.y);
    splitbf(x1.z, h4.z, l4.z); splitbf(x1.w, h4.w, l4.w);
    *(ushort4*)&XbH[row][lane32 * 4] = h4;
    *(ushort4*)&XbL[row][lane32 * 4] = l4;
    splitbf(a.x, h4.x, l4.x); splitbf(a.y, h4.y, l4.y);
    splitbf(a.z, h4.z, l4.z); splitbf(a.w, h4.w, l4.w);
    *(ushort4*)&XbH[row][128 + lane32 * 4] = h4;
    *(ushort4*)&XbL[row][128 + lane32 * 4] = l4;
  };

  if (bf) {
    const unsigned short* entp = (const unsigned short*)ent;
    int row0 = grp, row1 = grp + 8, row2 = grp + 16;  // row2 only for wv<2
    uint2 raw0[11], raw1[11], raw2[11];
    // issue ALL loads back-to-back (22 or 33 in flight)
    raw0[0] = *(const uint2*)(entp + (long)NodeIdL[row0] * 128 + lane32 * 4);
#pragma unroll
    for (int k = 0; k < 10; ++k)
      raw0[1 + k] = *(const uint2*)(entp + (long)EAdjL[row0 * 10 + k] * 128 + lane32 * 4);
    raw1[0] = *(const uint2*)(entp + (long)NodeIdL[row1] * 128 + lane32 * 4);
#pragma unroll
    for (int k = 0; k < 10; ++k)
      raw1[1 + k] = *(const uint2*)(entp + (long)EAdjL[row1 * 10 + k] * 128 + lane32 * 4);
    if (wv < 2) {
      raw2[0] = *(const uint2*)(entp + (long)NodeIdL[row2] * 128 + lane32 * 4);
#pragma unroll
      for (int k = 0; k < 10; ++k)
        raw2[1 + k] = *(const uint2*)(entp + (long)EAdjL[row2 * 10 + k] * 128 + lane32 * 4);
    }
    // consume in issue order
    consume(row0, raw0);
    consume(row1, raw1);
    if (wv < 2) consume(row2, raw2);
  } else {
    // f32 fallback (correctness path; bench input is bf16)
#pragma unroll
    for (int i = 0; i < 3; ++i) {
      int row = grp + i * 8;
      if (row < 20) {
        int node = NodeIdL[row];
        float4 x1 = ldf4(ent, (long)node * 128 + lane32 * 4, bf);
        float4 a = {0.f, 0.f, 0.f, 0.f};
#pragma unroll
        for (int k = 0; k < 10; ++k) {
          int an = EAdjL[row * 10 + k], rn = RAdjL[row * 10 + k];
          float4 e = ldf4(ent, (long)an * 128 + lane32 * 4, bf);
          const float4 r = *(const float4*)&relf[(long)rn * 128 + lane32 * 4];
          a.x += e.x + r.x;
          a.y += e.y + r.y;
          a.z += e.z + r.z;
          a.w += e.w + r.w;
        }
        ushort4 h4, l4;
        splitbf(x1.x, h4.x, l4.x); splitbf(x1.y, h4.y, l4.y);
        splitbf(x1.z, h4.z, l4.z); splitbf(x1.w, h4.w, l4.w);
        *(ushort4*)&XbH[row][lane32 * 4] = h4;
        *(ushort4*)&XbL[row][lane32 * 4] = l4;
        splitbf(a.x, h4.x, l4.x); splitbf(a.y, h4.y, l4.y);
        splitbf(a.z, h4.z, l4.z); splitbf(a.w, h4.w, l4.w);
        *(ushort4*)&XbH[row][128 + lane32 * 4] = h4;
        *(ushort4*)&XbL[row][128 + lane32 * 4] = l4;
      }
    }
  }
  __syncthreads();

  // --- Stage B: H = tanh(X @ Wanc^T + b), [20(pad32) x 256] @ [256->128] ---
  {
    int n0 = wv * 32 + r16, n1 = n0 + 16;
    int arow0 = r16, arow1 = 16 + (r16 & 3);   // mt=1 aliases rows 16-19
    f32x4 acc[2][2] = {};
    for (int kt = 0; kt < 8; ++kt) {
      long w0 = ((long)(kt * 128 + n0)) * 32 + khh * 8;
      long w1 = ((long)(kt * 128 + n1)) * 32 + khh * 8;
      short8v b0h = *(const short8v*)(WAH + w0);
      short8v b0l = *(const short8v*)(WAL + w0);
      short8v b1h = *(const short8v*)(WAH + w1);
      short8v b1l = *(const short8v*)(WAL + w1);
#pragma unroll
      for (int mt = 0; mt < 2; ++mt) {
        int ar = (mt == 0) ? arow0 : arow1;
        short8v ahi = *(const short8v*)&XbH[ar][kt * 32 + khh * 8];
        short8v alo = *(const short8v*)&XbL[ar][kt * 32 + khh * 8];
        acc[mt][0] = __builtin_amdgcn_mfma_f32_16x16x32_bf16(ahi, b0h, acc[mt][0], 0, 0, 0);
        acc[mt][0] = __builtin_amdgcn_mfma_f32_16x16x32_bf16(ahi, b0l, acc[mt][0], 0, 0, 0);
        acc[mt][0] = __builtin_amdgcn_mfma_f32_16x16x32_bf16(alo, b0h, acc[mt][0], 0, 0, 0);
        acc[mt][1] = __builtin_amdgcn_mfma_f32_16x16x32_bf16(ahi, b1h, acc[mt][1], 0, 0, 0);
        acc[mt][1] = __builtin_amdgcn_mfma_f32_16x16x32_bf16(ahi, b1l, acc[mt][1], 0, 0, 0);
        acc[mt][1] = __builtin_amdgcn_mfma_f32_16x16x32_bf16(alo, b1h, acc[mt][1], 0, 0, 0);
      }
    }
    float bc0 = ws[OFF_BANC + n0], bc1 = ws[OFF_BANC + n1];
#pragma unroll
    for (int mt = 0; mt < 2; ++mt)
#pragma unroll
      for (int j = 0; j < 4; ++j) {
        int r = mt * 16 + khh * 4 + j;
        if (r < 20) {
          unsigned short hi, lo;
          float h0 = tanhf(acc[mt][0][j] + bc0);
          splitbf(h0, hi, lo);
          Hhi[r][n0] = hi; Hlo[r][n0] = lo;
          float h1 = tanhf(acc[mt][1][j] + bc1);
          splitbf(h1, hi, lo);
          Hhi[r][n1] = hi; Hlo[r][n1] = lo;
        }
      }
  }
  __syncthreads();

  // --- Stage C: logits = elu(H@Waw1^T+b1)@w2 + b2, [20(pad32)x128]@[128->128] ---
  {
    int n0 = wv * 32 + r16, n1 = n0 + 16;
    int hrow0 = r16, hrow1 = 16 + (r16 & 3);
    float b10 = ws[OFF_BAW1 + n0], b11 = ws[OFF_BAW1 + n1];
    float w20 = ws[OFF_WAW2 + n0], w21 = ws[OFF_WAW2 + n1];
    f32x4 ac[2][2] = {};
    for (int kt = 0; kt < 4; ++kt) {
      long w0 = ((long)(kt * 128 + n0)) * 32 + khh * 8;
      long w1 = ((long)(kt * 128 + n1)) * 32 + khh * 8;
      short8v b0h = *(const short8v*)(W1H + w0);
      short8v b0l = *(const short8v*)(W1L + w0);
      short8v b1h = *(const short8v*)(W1H + w1);
      short8v b1l = *(const short8v*)(W1L + w1);
#pragma unroll
      for (int mt = 0; mt < 2; ++mt) {
        int hr = (mt == 0) ? hrow0 : hrow1;
        short8v ahi = *(const short8v*)&Hhi[hr][kt * 32 + khh * 8];
        short8v alo = *(const short8v*)&Hlo[hr][kt * 32 + khh * 8];
        ac[mt][0] = __builtin_amdgcn_mfma_f32_16x16x32_bf16(ahi, b0h, ac[mt][0], 0, 0, 0);
        ac[mt][0] = __builtin_amdgcn_mfma_f32_16x16x32_bf16(ahi, b0l, ac[mt][0], 0, 0, 0);
        ac[mt][0] = __builtin_amdgcn_mfma_f32_16x16x32_bf16(alo, b0h, ac[mt][0], 0, 0, 0);
        ac[mt][1] = __builtin_amdgcn_mfma_f32_16x16x32_bf16(ahi, b1h, ac[mt][1], 0, 0, 0);
        ac[mt][1] = __builtin_amdgcn_mfma_f32_16x16x32_bf16(ahi, b1l, ac[mt][1], 0, 0, 0);
        ac[mt][1] = __builtin_amdgcn_mfma_f32_16x16x32_bf16(alo, b1h, ac[mt][1], 0, 0, 0);
      }
    }
#pragma unroll
    for (int mt = 0; mt < 2; ++mt)
#pragma unroll
      for (int j = 0; j < 4; ++j) {
        float v = eluf(ac[mt][0][j] + b10) * w20 + eluf(ac[mt][1][j] + b11) * w21;
        v += __shfl_xor(v, 1);
        v += __shfl_xor(v, 2);
        v += __shfl_xor(v, 4);
        v += __shfl_xor(v, 8);
        int r = mt * 16 + khh * 4 + j;
        if (r16 == 0 && r < 20) LGp[wv][r] = v;
      }
  }
  __syncthreads();

  // --- Stage D: softmax over 20 anchors + weighted sum (128 threads) ---
  if (tid < 128) {
    float bw2 = ws[OFF_BAW2];
    float e[20], mx = -1e30f;
#pragma unroll
    for (int a = 0; a < 20; ++a) {
      e[a] = LGp[0][a] + LGp[1][a] + LGp[2][a] + LGp[3][a] + bw2;
      mx = fmaxf(mx, e[a]);
    }
    float s = 0.f;
#pragma unroll
    for (int a = 0; a < 20; ++a) { e[a] = expf(e[a] - mx); s += e[a]; }
    float inv = 1.0f / s;
    float o = 0.f;
#pragma unroll
    for (int a = 0; a < 20; ++a)
      o += e[a] * (bfh(Hhi[a][tid]) + bfh(Hlo[a][tid]));
    float* AE = ws + OFF_AE;
    AE[(long)blockIdx.x * 128 + tid] = o * inv;
  }
}

// ---- K5: final MLP --------------------------------------------------------
__global__ __launch_bounds__(256) void k_mlp(float* ws) {
  __shared__ __align__(16) float xt[16][256];
  __shared__ __align__(16) float h1[16][128];
  int tid = threadIdx.x;
  long r0 = (long)blockIdx.x * 16;
  const float* NE = ws + OFF_NE;
  const float* AE = ws + OFF_AE;
  for (int x = tid; x < 16 * 256; x += 256) {
    int c = x >> 8, k = x & 255;
    xt[c][k] = (k < 128) ? NE[(r0 + c) * 128 + k] : AE[(r0 + c) * 128 + (k - 128)];
  }
  __syncthreads();
  int j = tid & 127, half = tid >> 7;
  const float4* W1 = (const float4*)(ws + OFF_WM1P);
  float acc[8];
#pragma unroll
  for (int c = 0; c < 8; c++) acc[c] = 0.f;
  for (int k4 = 0; k4 < 64; k4++) {
    float4 w = W1[k4 * 128 + j];
#pragma unroll
    for (int c = 0; c < 8; c++) {
      const float4 xv = *(const float4*)&xt[half * 8 + c][k4 * 4];
      acc[c] += w.x * xv.x + w.y * xv.y + w.z * xv.z + w.w * xv.w;
    }
  }
  float b1 = ws[OFF_BM1 + j];
#pragma unroll
  for (int c = 0; c < 8; c++) h1[half * 8 + c][j] = eluf(acc[c] + b1);
  __syncthreads();
  const float4* W2 = (const float4*)(ws + OFF_WM2P);
  float a2[8];
#pragma unroll
  for (int c = 0; c < 8; c++) a2[c] = 0.f;
  for (int k4 = 0; k4 < 32; k4++) {
    float4 w = W2[k4 * 128 + j];
#pragma unroll
    for (int c = 0; c < 8; c++) {
      const float4 xv = *(const float4*)&h1[half * 8 + c][k4 * 4];
      a2[c] += w.x * xv.x + w.y * xv.y + w.z * xv.z + w.w * xv.w;
    }
  }
  float b2 = ws[OFF_BM2 + j];
  float* MO = ws + OFF_MO;
#pragma unroll
  for (int c = 0; c < 8; c++) MO[(r0 + half * 8 + c) * 128 + j] = eluf(a2[c] + b2);
}

// ---- K6: user mean + scores ----------------------------------------------
__global__ __launch_bounds__(128) void k_score(const float* ws, void* out) {
  const int bf = ((const int*)ws)[0];
  int b = blockIdx.x;
  int d = threadIdx.x;
  const float* MO = ws + OFF_MO;
  float u = 0.f;
  for (int t = 0; t < UC_; t++) u += MO[(long)(NCAND + b * UC_ + t) * 128 + d];
  u *= (1.0f / UC_);
  __shared__ float red[2];
  for (int s = 0; s < S_; s++) {
    float p = MO[(long)(b * S_ + s) * 128 + d] * u;
#pragma unroll
    for (int o = 32; o > 0; o >>= 1) p += __shfl_down(p, o, 64);
    if ((d & 63) == 0) red[d >> 6] = p;
    __syncthreads();
    if (d == 0) {
      float v = red[0] + red[1];
      if (bf)
        ((__hip_bfloat16*)out)[b * S_ + s] = __float2bfloat16(v);
      else
        ((float*)out)[b * S_ + s] = v;
    }
    __syncthreads();
  }
}

extern "C" void kernel_launch(void* const* d_in, const int* in_sizes, int n_in,
                              void* d_out, int out_size, void* d_ws, size_t ws_size,
                              hipStream_t stream) {
  (void)in_sizes; (void)n_in; (void)out_size; (void)ws_size;
  const void* titles = d_in[0];
  const void* ent    = d_in[1];
  const void* rel    = d_in[2];
  const void* Wnc1 = d_in[3];  const void* bnc1 = d_in[4];
  const void* Wnc2 = d_in[5];  const void* bnc2 = d_in[6];
  const void* Wanc = d_in[7];  const void* banc = d_in[8];
  const void* Waw1 = d_in[9];  const void* baw1 = d_in[10];
  const void* Waw2 = d_in[11]; const void* baw2 = d_in[12];
  const void* Wm1  = d_in[13]; const void* bm1  = d_in[14];
  const void* Wm2  = d_in[15]; const void* bm2  = d_in[16];
  const int* cand  = (const int*)d_in[17];
  const int* clk   = (const int*)d_in[18];
  const int* canda = (const int*)d_in[19];
  const int* clka  = (const int*)d_in[20];
  const int* eadj  = (const int*)d_in[21];
  const int* radj  = (const int*)d_in[22];
  float* ws = (float*)d_ws;

  k_detect<<<1, 256, 0, stream>>>(ent, (int*)d_ws);
  k_prep<<<256, 256, 0, stream>>>(Wnc1, bnc1, Wnc2, bnc2, Wanc, banc, Waw1, baw1,
                                  Waw2, baw2, Wm1, bm1, Wm2, bm2, rel, ws);
  k_news<<<NNEWS / 8, 128, 0, stream>>>(titles, cand, clk, ws);
  k_anchor<<<NNEWS, 256, 0, stream>>>(ent, canda, clka, eadj, radj, ws);
  k_mlp<<<NNEWS / 16, 256, 0, stream>>>(ws);
  k_score<<<B_, 128, 0, stream>>>(ws, d_out);
}